// Round 1
// baseline (5843.350 us; speedup 1.0000x reference)
//
#include <hip/hip_runtime.h>

#define NF 128

// ---------------- degree: one float atomicAdd per edge ----------------
__global__ void deg_kernel(const int* __restrict__ dst, float* __restrict__ deg, int E) {
    int e = blockIdx.x * blockDim.x + threadIdx.x;
    if (e < E) atomicAdd(&deg[dst[e]], 1.0f);
}

// ---------------- scatter-add features: 32 threads per edge (float4 chunks) ----------------
__global__ void scatter_kernel(const float* __restrict__ feat, const int* __restrict__ src,
                               const int* __restrict__ dst, float* __restrict__ agg, int E) {
    long long tid = (long long)blockIdx.x * blockDim.x + threadIdx.x;
    int e = (int)(tid >> 5);   // 32 float4-chunks cover 128 floats
    int c = (int)(tid & 31);
    if (e >= E) return;
    int s = src[e], d = dst[e];
    const float4 v = *(const float4*)(feat + (long long)s * NF + c * 4);
    float* out = agg + (long long)d * NF + c * 4;
    atomicAdd(out + 0, v.x);
    atomicAdd(out + 1, v.y);
    atomicAdd(out + 2, v.z);
    atomicAdd(out + 3, v.w);
}

// ---------------- SAGE layer: out = relu(agg/deg @ Wl + xin @ Wr + b) ----------------
// 8 nodes per block, 256 threads: col = t&127, half = t>>7; each thread does 4 nodes.
__global__ __launch_bounds__(256) void sage_layer_kernel(
    const float* __restrict__ agg, const float* __restrict__ deg,
    const float* __restrict__ xin, const float* __restrict__ Wl,
    const float* __restrict__ Wr, const float* __restrict__ bias,
    float* __restrict__ out, int n)
{
    __shared__ float a_s[8][NF];
    __shared__ float x_s[8][NF];
    __shared__ float invd_s[8];
    int t = threadIdx.x;
    int node0 = blockIdx.x * 8;

    #pragma unroll
    for (int i = 0; i < 4; i++) {
        int idx = t + i * 256;
        int nn = idx >> 7, k = idx & 127;
        a_s[nn][k] = agg[(long long)(node0 + nn) * NF + k];
        x_s[nn][k] = xin[(long long)(node0 + nn) * NF + k];
    }
    if (t < 8) invd_s[t] = 1.0f / fmaxf(deg[node0 + t], 1.0f);
    __syncthreads();

    int col = t & 127, half = t >> 7;
    float sa[4] = {0.f, 0.f, 0.f, 0.f};
    float sx[4] = {0.f, 0.f, 0.f, 0.f};
    for (int k = 0; k < NF; k++) {
        float wl = Wl[k * NF + col];
        float wr = Wr[k * NF + col];
        #pragma unroll
        for (int j = 0; j < 4; j++) {
            sa[j] += a_s[half * 4 + j][k] * wl;
            sx[j] += x_s[half * 4 + j][k] * wr;
        }
    }
    float bcol = bias[col];
    #pragma unroll
    for (int j = 0; j < 4; j++) {
        int nn = half * 4 + j;
        out[(long long)(node0 + nn) * NF + col] = fmaxf(sa[j] * invd_s[nn] + sx[j] + bcol, 0.f);
    }
}

// ---------------- layer 2 + FC fused: out[n,2] = relu(...) @ Wfc + bfc ----------------
__global__ __launch_bounds__(256) void sage_layer2_fc_kernel(
    const float* __restrict__ agg, const float* __restrict__ deg,
    const float* __restrict__ h1, const float* __restrict__ Wl,
    const float* __restrict__ Wr, const float* __restrict__ bias,
    const float* __restrict__ Wfc, const float* __restrict__ bfc,
    float* __restrict__ out, int n)
{
    __shared__ float a_s[8][NF];
    __shared__ float x_s[8][NF];
    __shared__ float h_s[8][NF];
    __shared__ float invd_s[8];
    __shared__ float red[256][2];
    int t = threadIdx.x;
    int node0 = blockIdx.x * 8;

    #pragma unroll
    for (int i = 0; i < 4; i++) {
        int idx = t + i * 256;
        int nn = idx >> 7, k = idx & 127;
        a_s[nn][k] = agg[(long long)(node0 + nn) * NF + k];
        x_s[nn][k] = h1[(long long)(node0 + nn) * NF + k];
    }
    if (t < 8) invd_s[t] = 1.0f / fmaxf(deg[node0 + t], 1.0f);
    __syncthreads();

    int col = t & 127, half = t >> 7;
    float sa[4] = {0.f, 0.f, 0.f, 0.f};
    float sx[4] = {0.f, 0.f, 0.f, 0.f};
    for (int k = 0; k < NF; k++) {
        float wl = Wl[k * NF + col];
        float wr = Wr[k * NF + col];
        #pragma unroll
        for (int j = 0; j < 4; j++) {
            sa[j] += a_s[half * 4 + j][k] * wl;
            sx[j] += x_s[half * 4 + j][k] * wr;
        }
    }
    float bcol = bias[col];
    #pragma unroll
    for (int j = 0; j < 4; j++) {
        int nn = half * 4 + j;
        h_s[nn][col] = fmaxf(sa[j] * invd_s[nn] + sx[j] + bcol, 0.f);
    }
    __syncthreads();

    // FC: each group of 32 threads handles one node; 2 output columns.
    int nn2 = t >> 5, lane = t & 31;
    float p0 = 0.f, p1 = 0.f;
    for (int k = lane; k < NF; k += 32) {
        float h = h_s[nn2][k];
        p0 += h * Wfc[2 * k + 0];
        p1 += h * Wfc[2 * k + 1];
    }
    red[t][0] = p0;
    red[t][1] = p1;
    __syncthreads();
    for (int s = 16; s; s >>= 1) {
        if (lane < s) {
            red[t][0] += red[t + s][0];
            red[t][1] += red[t + s][1];
        }
        __syncthreads();
    }
    if (lane == 0) {
        out[(long long)(node0 + nn2) * 2 + 0] = red[t][0] + bfc[0];
        out[(long long)(node0 + nn2) * 2 + 1] = red[t][1] + bfc[1];
    }
}

extern "C" void kernel_launch(void* const* d_in, const int* in_sizes, int n_in,
                              void* d_out, int out_size, void* d_ws, size_t ws_size,
                              hipStream_t stream) {
    const float* x   = (const float*)d_in[0];
    const int*   ei  = (const int*)d_in[1];
    const float* W1l = (const float*)d_in[2];
    const float* b1  = (const float*)d_in[3];
    const float* W1r = (const float*)d_in[4];
    const float* W2l = (const float*)d_in[5];
    const float* b2  = (const float*)d_in[6];
    const float* W2r = (const float*)d_in[7];
    const float* Wfc = (const float*)d_in[8];
    const float* bfc = (const float*)d_in[9];

    const int n = in_sizes[0] / NF;   // 100000
    const int E = in_sizes[1] / 2;    // 1600000
    const int* src = ei;
    const int* dst = ei + E;

    float* agg = (float*)d_ws;
    float* deg = agg + (size_t)n * NF;
    float* h1  = deg + n;

    // zero agg + deg (contiguous)
    hipMemsetAsync(agg, 0, ((size_t)n * NF + n) * sizeof(float), stream);

    deg_kernel<<<(E + 255) / 256, 256, 0, stream>>>(dst, deg, E);

    long long sc_threads = (long long)E * 32;
    int sc_blocks = (int)((sc_threads + 255) / 256);
    scatter_kernel<<<sc_blocks, 256, 0, stream>>>(x, src, dst, agg, E);

    sage_layer_kernel<<<n / 8, 256, 0, stream>>>(agg, deg, x, W1l, W1r, b1, h1, n);

    // re-zero agg only (deg is reused)
    hipMemsetAsync(agg, 0, (size_t)n * NF * sizeof(float), stream);

    scatter_kernel<<<sc_blocks, 256, 0, stream>>>(h1, src, dst, agg, E);

    sage_layer2_fc_kernel<<<n / 8, 256, 0, stream>>>(agg, deg, h1, W2l, W2r, b2,
                                                     Wfc, bfc, (float*)d_out, n);
}

// Round 2
// 749.898 us; speedup vs baseline: 7.7922x; 7.7922x over previous
//
#include <hip/hip_runtime.h>

#define NF 128

// ---------------- in-degree histogram (int atomics) ----------------
__global__ void deg_kernel(const int* __restrict__ dst, int* __restrict__ deg, int E) {
    int e = blockIdx.x * blockDim.x + threadIdx.x;
    if (e < E) atomicAdd(&deg[dst[e]], 1);
}

// ---------------- single-block exclusive scan over n counts ----------------
__global__ __launch_bounds__(1024) void scan_kernel(const int* __restrict__ deg,
                                                    int* __restrict__ row_ptr, int n, int E) {
    __shared__ int ssum[1024];
    int t = threadIdx.x;
    int chunk = (n + 1023) / 1024;
    int beg = t * chunk, end = min(beg + chunk, n);
    int s = 0;
    for (int i = beg; i < end; i++) s += deg[i];
    ssum[t] = s;
    __syncthreads();
    // Hillis-Steele inclusive scan over 1024 thread sums
    for (int off = 1; off < 1024; off <<= 1) {
        int v = (t >= off) ? ssum[t - off] : 0;
        __syncthreads();
        ssum[t] += v;
        __syncthreads();
    }
    int run = (t == 0) ? 0 : ssum[t - 1];
    for (int i = beg; i < end; i++) { row_ptr[i] = run; run += deg[i]; }
    if (t == 0) row_ptr[n] = E;
}

// ---------------- CSR fill via per-node cursor ----------------
__global__ void fill_kernel(const int* __restrict__ src, const int* __restrict__ dst,
                            const int* __restrict__ row_ptr, int* __restrict__ cursor,
                            int* __restrict__ adj, int E) {
    int e = blockIdx.x * blockDim.x + threadIdx.x;
    if (e >= E) return;
    int d = dst[e];
    int pos = atomicAdd(&cursor[d], 1);
    adj[row_ptr[d] + pos] = src[e];
}

// ---------------- fused: gather-mean + dual GEMV + bias + relu (+ optional FC) ----------------
// 8 nodes / block, 256 threads.
template <bool FC>
__global__ __launch_bounds__(256) void sage_fused_kernel(
    const float* __restrict__ xin, const int* __restrict__ row_ptr,
    const int* __restrict__ adj, const float* __restrict__ Wl,
    const float* __restrict__ Wr, const float* __restrict__ bias,
    const float* __restrict__ Wfc, const float* __restrict__ bfc,
    float* __restrict__ out, int n)
{
    __shared__ float a_s[8][NF];
    __shared__ float x_s[8][NF];
    int t = threadIdx.x;
    int node0 = blockIdx.x * 8;

    // ---- gather phase: 32-lane group per node, float4 per lane (128 floats/row)
    {
        int g = t >> 5, lane = t & 31;
        int node = node0 + g;
        int beg = row_ptr[node], end = row_ptr[node + 1];
        float4 acc = make_float4(0.f, 0.f, 0.f, 0.f);
        int i = beg;
        for (; i + 1 < end; i += 2) {   // 2-way: two x-row loads in flight
            int nb0 = adj[i], nb1 = adj[i + 1];
            const float4 v0 = *(const float4*)(xin + (long long)nb0 * NF + lane * 4);
            const float4 v1 = *(const float4*)(xin + (long long)nb1 * NF + lane * 4);
            acc.x += v0.x + v1.x; acc.y += v0.y + v1.y;
            acc.z += v0.z + v1.z; acc.w += v0.w + v1.w;
        }
        if (i < end) {
            int nb = adj[i];
            const float4 v = *(const float4*)(xin + (long long)nb * NF + lane * 4);
            acc.x += v.x; acc.y += v.y; acc.z += v.z; acc.w += v.w;
        }
        float invd = 1.0f / fmaxf((float)(end - beg), 1.0f);
        acc.x *= invd; acc.y *= invd; acc.z *= invd; acc.w *= invd;
        *(float4*)&a_s[g][lane * 4] = acc;
    }

    // ---- self-features into LDS
    #pragma unroll
    for (int i = 0; i < 4; i++) {
        int idx = t + i * 256;
        int nn = idx >> 7, k = idx & 127;
        x_s[nn][k] = xin[(long long)(node0 + nn) * NF + k];
    }
    __syncthreads();

    // ---- dual GEMV: col = t&127, half = t>>7, 4 nodes per thread
    int col = t & 127, half = t >> 7;
    float sa[4] = {0.f, 0.f, 0.f, 0.f};
    float sx[4] = {0.f, 0.f, 0.f, 0.f};
    for (int k = 0; k < NF; k++) {
        float wl = Wl[k * NF + col];
        float wr = Wr[k * NF + col];
        #pragma unroll
        for (int j = 0; j < 4; j++) {
            sa[j] += a_s[half * 4 + j][k] * wl;
            sx[j] += x_s[half * 4 + j][k] * wr;
        }
    }
    float bcol = bias[col];

    if (!FC) {
        #pragma unroll
        for (int j = 0; j < 4; j++) {
            int nn = half * 4 + j;
            out[(long long)(node0 + nn) * NF + col] = fmaxf(sa[j] + sx[j] + bcol, 0.f);
        }
    } else {
        __syncthreads();   // all GEMV reads of a_s done before overwrite
        #pragma unroll
        for (int j = 0; j < 4; j++) {
            int nn = half * 4 + j;
            a_s[nn][col] = fmaxf(sa[j] + sx[j] + bcol, 0.f);
        }
        __syncthreads();
        // FC: 32 lanes per node, shuffle-reduce
        int nn2 = t >> 5, lane = t & 31;
        float p0 = 0.f, p1 = 0.f;
        for (int k = lane; k < NF; k += 32) {
            float h = a_s[nn2][k];
            p0 += h * Wfc[2 * k + 0];
            p1 += h * Wfc[2 * k + 1];
        }
        for (int s = 16; s; s >>= 1) {
            p0 += __shfl_down(p0, s, 32);
            p1 += __shfl_down(p1, s, 32);
        }
        if (lane == 0) {
            out[(long long)(node0 + nn2) * 2 + 0] = p0 + bfc[0];
            out[(long long)(node0 + nn2) * 2 + 1] = p1 + bfc[1];
        }
    }
}

extern "C" void kernel_launch(void* const* d_in, const int* in_sizes, int n_in,
                              void* d_out, int out_size, void* d_ws, size_t ws_size,
                              hipStream_t stream) {
    const float* x   = (const float*)d_in[0];
    const int*   ei  = (const int*)d_in[1];
    const float* W1l = (const float*)d_in[2];
    const float* b1  = (const float*)d_in[3];
    const float* W1r = (const float*)d_in[4];
    const float* W2l = (const float*)d_in[5];
    const float* b2  = (const float*)d_in[6];
    const float* W2r = (const float*)d_in[7];
    const float* Wfc = (const float*)d_in[8];
    const float* bfc = (const float*)d_in[9];

    const int n = in_sizes[0] / NF;   // 100000
    const int E = in_sizes[1] / 2;    // 1600000
    const int* src = ei;
    const int* dst = ei + E;

    // workspace: h1 | deg | cursor | row_ptr | adj   (~58.8 MB)
    float* h1      = (float*)d_ws;
    int*   deg     = (int*)(h1 + (size_t)n * NF);
    int*   cursor  = deg + n;
    int*   row_ptr = cursor + n;
    int*   adj     = row_ptr + (n + 1);

    // zero deg + cursor (contiguous 2n ints)
    hipMemsetAsync(deg, 0, (size_t)2 * n * sizeof(int), stream);

    int eb = (E + 255) / 256;
    deg_kernel<<<eb, 256, 0, stream>>>(dst, deg, E);
    scan_kernel<<<1, 1024, 0, stream>>>(deg, row_ptr, n, E);
    fill_kernel<<<eb, 256, 0, stream>>>(src, dst, row_ptr, cursor, adj, E);

    // layer 1: x -> h1
    sage_fused_kernel<false><<<n / 8, 256, 0, stream>>>(
        x, row_ptr, adj, W1l, W1r, b1, nullptr, nullptr, h1, n);

    // layer 2 + FC: h1 -> out
    sage_fused_kernel<true><<<n / 8, 256, 0, stream>>>(
        h1, row_ptr, adj, W2l, W2r, b2, Wfc, bfc, (float*)d_out, n);
}

// Round 3
// 705.266 us; speedup vs baseline: 8.2853x; 1.0633x over previous
//
#include <hip/hip_runtime.h>

#define NF 128

typedef unsigned short u16;
using u16x4 = __attribute__((ext_vector_type(4))) u16;
using u16x8 = __attribute__((ext_vector_type(8))) u16;
using s16x8 = __attribute__((ext_vector_type(8))) short;
using f32x4 = __attribute__((ext_vector_type(4))) float;

__device__ inline float b2f(u16 b) {
    union { unsigned u; float f; } c; c.u = (unsigned)b << 16; return c.f;
}
__device__ inline u16 f2b(float f) {
    union { float f; unsigned u; } c; c.f = f;
    unsigned u = c.u;
    u += 0x7FFFu + ((u >> 16) & 1u);   // round-to-nearest-even
    return (u16)(u >> 16);
}

// ---------------- in-degree histogram (int atomics) ----------------
__global__ void deg_kernel(const int* __restrict__ dst, int* __restrict__ deg, int E) {
    int e = blockIdx.x * blockDim.x + threadIdx.x;
    if (e < E) atomicAdd(&deg[dst[e]], 1);
}

// ---------------- single-block exclusive scan over n counts ----------------
__global__ __launch_bounds__(1024) void scan_kernel(const int* __restrict__ deg,
                                                    int* __restrict__ row_ptr, int n, int E) {
    __shared__ int ssum[1024];
    int t = threadIdx.x;
    int chunk = (n + 1023) / 1024;
    int beg = t * chunk, end = min(beg + chunk, n);
    int s = 0;
    for (int i = beg; i < end; i++) s += deg[i];
    ssum[t] = s;
    __syncthreads();
    for (int off = 1; off < 1024; off <<= 1) {
        int v = (t >= off) ? ssum[t - off] : 0;
        __syncthreads();
        ssum[t] += v;
        __syncthreads();
    }
    int run = (t == 0) ? 0 : ssum[t - 1];
    for (int i = beg; i < end; i++) { row_ptr[i] = run; run += deg[i]; }
    if (t == 0) row_ptr[n] = E;
}

// ---------------- CSR fill via per-node cursor ----------------
__global__ void fill_kernel(const int* __restrict__ src, const int* __restrict__ dst,
                            const int* __restrict__ row_ptr, int* __restrict__ cursor,
                            int* __restrict__ adj, int E) {
    int e = blockIdx.x * blockDim.x + threadIdx.x;
    if (e >= E) return;
    int d = dst[e];
    int pos = atomicAdd(&cursor[d], 1);
    adj[row_ptr[d] + pos] = src[e];
}

// ---------------- fp32 -> bf16 cast of features ----------------
__global__ void cast_x_kernel(const float* __restrict__ in, u16* __restrict__ out, int nvec) {
    int i = blockIdx.x * blockDim.x + threadIdx.x;
    if (i >= nvec) return;
    const float4 v0 = ((const float4*)in)[2 * i];
    const float4 v1 = ((const float4*)in)[2 * i + 1];
    u16x8 o;
    o[0] = f2b(v0.x); o[1] = f2b(v0.y); o[2] = f2b(v0.z); o[3] = f2b(v0.w);
    o[4] = f2b(v1.x); o[5] = f2b(v1.y); o[6] = f2b(v1.z); o[7] = f2b(v1.w);
    ((u16x8*)out)[i] = o;
}

// ---------------- weights: fp32 [K=128][N=128] -> bf16 transposed [N][K] ----------------
__global__ void cast_wt_kernel(const float* __restrict__ w0, const float* __restrict__ w1,
                               const float* __restrict__ w2, const float* __restrict__ w3,
                               u16* __restrict__ o0, u16* __restrict__ o1,
                               u16* __restrict__ o2, u16* __restrict__ o3) {
    int m = blockIdx.y;
    const float* w = (m == 0) ? w0 : (m == 1) ? w1 : (m == 2) ? w2 : w3;
    u16* o = (m == 0) ? o0 : (m == 1) ? o1 : (m == 2) ? o2 : o3;
    int i = blockIdx.x * 256 + threadIdx.x;   // 0..16383
    int k = i >> 7, nc = i & 127;
    o[nc * NF + k] = f2b(w[k * NF + nc]);
}

// ---------------- fused layer: gather-mean + dual MFMA GEMM + bias + relu (+FC) ----------------
// 64 nodes / block, 256 threads (4 waves x 16 output rows).
template <bool FC>
__global__ __launch_bounds__(256) void sage_mfma_kernel(
    const u16* __restrict__ xin,       // [n][128] bf16
    const int* __restrict__ row_ptr,
    const int* __restrict__ adj,
    const u16* __restrict__ Wtl,       // [128][128] bf16, transposed: Wt[n][k]
    const u16* __restrict__ Wtr,
    const float* __restrict__ bias,
    const float* __restrict__ Wfc,     // [128][2] f32
    const float* __restrict__ bfc,     // [2] f32
    u16* __restrict__ hout,            // [n][128] bf16 (layer 1)
    float* __restrict__ out,           // [n][2] f32 (layer 2)
    int n)
{
    constexpr int MT = 64;
    constexpr int LDK = 136;           // 272 B rows: 16B-aligned, 2-way bank aliasing only
    __shared__ u16 A_s[MT][LDK];       // 17.4 KB
    __shared__ u16 W_s[NF][LDK];       // 34.8 KB

    int t = threadIdx.x;
    int node0 = blockIdx.x * MT;

    // ---- stage Wl -> W_s
    #pragma unroll
    for (int i = 0; i < 8; i++) {
        int idx = t + i * 256;                 // 2048 chunks of 16 B
        int row = idx >> 4, ch = idx & 15;
        *(u16x8*)&W_s[row][ch * 8] = ((const u16x8*)Wtl)[row * 16 + ch];
    }

    // ---- gather mean into A_s: 8 groups of 32 lanes, 8 nodes each
    {
        int g = t >> 5, lane = t & 31;
        for (int m8 = 0; m8 < 8; m8++) {
            int m = g * 8 + m8;
            int node = node0 + m;
            float a0 = 0.f, a1 = 0.f, a2 = 0.f, a3 = 0.f, invd = 0.f;
            if (node < n) {
                int beg = row_ptr[node], end = row_ptr[node + 1];
                int i = beg;
                for (; i + 1 < end; i += 2) {
                    int nb0 = adj[i], nb1 = adj[i + 1];
                    u16x4 v0 = *(const u16x4*)(xin + (long long)nb0 * NF + lane * 4);
                    u16x4 v1 = *(const u16x4*)(xin + (long long)nb1 * NF + lane * 4);
                    a0 += b2f(v0[0]) + b2f(v1[0]);
                    a1 += b2f(v0[1]) + b2f(v1[1]);
                    a2 += b2f(v0[2]) + b2f(v1[2]);
                    a3 += b2f(v0[3]) + b2f(v1[3]);
                }
                if (i < end) {
                    int nb = adj[i];
                    u16x4 v = *(const u16x4*)(xin + (long long)nb * NF + lane * 4);
                    a0 += b2f(v[0]); a1 += b2f(v[1]); a2 += b2f(v[2]); a3 += b2f(v[3]);
                }
                invd = 1.0f / fmaxf((float)(end - beg), 1.0f);
            }
            u16x4 o;
            o[0] = f2b(a0 * invd); o[1] = f2b(a1 * invd);
            o[2] = f2b(a2 * invd); o[3] = f2b(a3 * invd);
            *(u16x4*)&A_s[m][lane * 4] = o;
        }
    }
    __syncthreads();

    // ---- MFMA pass 1: acc = A_agg @ Wl
    int l = t & 63;
    int lr = l & 15;                 // fragment row (A) / col (B,C)
    int lko = (l >> 4) * 8;          // k offset within fragment
    int m0 = (t >> 6) * 16;          // wave's 16 output rows

    f32x4 acc[8];
    #pragma unroll
    for (int f = 0; f < 8; f++) acc[f] = (f32x4)0.f;

    #pragma unroll
    for (int ks = 0; ks < NF; ks += 32) {
        s16x8 a = *(const s16x8*)&A_s[m0 + lr][ks + lko];
        #pragma unroll
        for (int f = 0; f < 8; f++) {
            s16x8 b = *(const s16x8*)&W_s[f * 16 + lr][ks + lko];
            acc[f] = __builtin_amdgcn_mfma_f32_16x16x32_bf16(a, b, acc[f], 0, 0, 0);
        }
    }
    __syncthreads();

    // ---- stage Wr -> W_s, self features -> A_s
    #pragma unroll
    for (int i = 0; i < 8; i++) {
        int idx = t + i * 256;
        int row = idx >> 4, ch = idx & 15;
        *(u16x8*)&W_s[row][ch * 8] = ((const u16x8*)Wtr)[row * 16 + ch];
    }
    #pragma unroll
    for (int i = 0; i < 4; i++) {
        int idx = t + i * 256;                 // 1024 chunks of 16 B
        int row = idx >> 4, ch = idx & 15;
        int node = node0 + row;
        u16x8 v = (u16x8)0;
        if (node < n) v = ((const u16x8*)(xin + (long long)node * NF))[ch];
        *(u16x8*)&A_s[row][ch * 8] = v;
    }
    __syncthreads();

    // ---- MFMA pass 2: acc += X @ Wr
    #pragma unroll
    for (int ks = 0; ks < NF; ks += 32) {
        s16x8 a = *(const s16x8*)&A_s[m0 + lr][ks + lko];
        #pragma unroll
        for (int f = 0; f < 8; f++) {
            s16x8 b = *(const s16x8*)&W_s[f * 16 + lr][ks + lko];
            acc[f] = __builtin_amdgcn_mfma_f32_16x16x32_bf16(a, b, acc[f], 0, 0, 0);
        }
    }

    // ---- bias + relu, stash result tile (bf16) back into A_s
    __syncthreads();
    int rowb = m0 + (l >> 4) * 4;    // C layout: row = (lane>>4)*4 + reg, col = lane&15
    #pragma unroll
    for (int f = 0; f < 8; f++) {
        float bc = bias[f * 16 + lr];
        #pragma unroll
        for (int r = 0; r < 4; r++) {
            float v = fmaxf(acc[f][r] + bc, 0.f);
            A_s[rowb + r][f * 16 + lr] = f2b(v);
        }
    }
    __syncthreads();

    if (!FC) {
        // coalesced bf16 write of h tile
        #pragma unroll
        for (int i = 0; i < 4; i++) {
            int idx = t + i * 256;
            int row = idx >> 4, ch = idx & 15;
            int node = node0 + row;
            if (node < n)
                ((u16x8*)(hout + (long long)node * NF))[ch] = *(const u16x8*)&A_s[row][ch * 8];
        }
    } else {
        // FC epilogue: 32 lanes per node, shuffle reduce, float2 store
        int g = t >> 5, lane = t & 31;
        float2 wfc[4];
        #pragma unroll
        for (int j = 0; j < 4; j++) wfc[j] = ((const float2*)Wfc)[lane * 4 + j];
        float bf0 = bfc[0], bf1 = bfc[1];
        for (int m8 = 0; m8 < 8; m8++) {
            int m = g * 8 + m8;
            float p0 = 0.f, p1 = 0.f;
            #pragma unroll
            for (int j = 0; j < 4; j++) {
                float h = b2f(A_s[m][lane * 4 + j]);
                p0 += h * wfc[j].x;
                p1 += h * wfc[j].y;
            }
            #pragma unroll
            for (int s = 16; s; s >>= 1) {
                p0 += __shfl_down(p0, s, 32);
                p1 += __shfl_down(p1, s, 32);
            }
            int node = node0 + m;
            if (lane == 0 && node < n)
                *(float2*)(out + (long long)node * 2) = make_float2(p0 + bf0, p1 + bf1);
        }
    }
}

extern "C" void kernel_launch(void* const* d_in, const int* in_sizes, int n_in,
                              void* d_out, int out_size, void* d_ws, size_t ws_size,
                              hipStream_t stream) {
    const float* x   = (const float*)d_in[0];
    const int*   ei  = (const int*)d_in[1];
    const float* W1l = (const float*)d_in[2];
    const float* b1  = (const float*)d_in[3];
    const float* W1r = (const float*)d_in[4];
    const float* W2l = (const float*)d_in[5];
    const float* b2  = (const float*)d_in[6];
    const float* W2r = (const float*)d_in[7];
    const float* Wfc = (const float*)d_in[8];
    const float* bfc = (const float*)d_in[9];

    const int n = in_sizes[0] / NF;   // 100000
    const int E = in_sizes[1] / 2;    // 1600000
    const int* src = ei;
    const int* dst = ei + E;

    // ws layout (16B-aligned pieces): x_bf16 | h1_bf16 | 4x Wt | deg | cursor | adj | row_ptr
    u16* x_bf   = (u16*)d_ws;
    u16* h1_bf  = x_bf + (size_t)n * NF;
    u16* Wt1l   = h1_bf + (size_t)n * NF;
    u16* Wt1r   = Wt1l + NF * NF;
    u16* Wt2l   = Wt1r + NF * NF;
    u16* Wt2r   = Wt2l + NF * NF;
    int* deg    = (int*)(Wt2r + NF * NF);
    int* cursor = deg + n;
    int* adj    = cursor + n;
    int* row_ptr= adj + E;

    // zero deg + cursor (contiguous 2n ints)
    hipMemsetAsync(deg, 0, (size_t)2 * n * sizeof(int), stream);

    int eb = (E + 255) / 256;
    deg_kernel<<<eb, 256, 0, stream>>>(dst, deg, E);
    scan_kernel<<<1, 1024, 0, stream>>>(deg, row_ptr, n, E);
    fill_kernel<<<eb, 256, 0, stream>>>(src, dst, row_ptr, cursor, adj, E);

    int nvec = n * NF / 8;
    cast_x_kernel<<<(nvec + 255) / 256, 256, 0, stream>>>(x, x_bf, nvec);
    cast_wt_kernel<<<dim3(64, 4), 256, 0, stream>>>(W1l, W1r, W2l, W2r,
                                                    Wt1l, Wt1r, Wt2l, Wt2r);

    int nb = (n + 63) / 64;
    // layer 1: x_bf -> h1_bf
    sage_mfma_kernel<false><<<nb, 256, 0, stream>>>(
        x_bf, row_ptr, adj, Wt1l, Wt1r, b1, nullptr, nullptr, h1_bf, nullptr, n);
    // layer 2 + FC: h1_bf -> out
    sage_mfma_kernel<true><<<nb, 256, 0, stream>>>(
        h1_bf, row_ptr, adj, Wt2l, Wt2r, b2, Wfc, bfc, nullptr, (float*)d_out, n);
}

// Round 5
// 486.011 us; speedup vs baseline: 12.0231x; 1.4511x over previous
//
#include <hip/hip_runtime.h>

#define NF 128          // features
#define NC 8            // chunks (one per XCD)
#define CF 16           // features per chunk

typedef unsigned short u16;
using u16x4 = __attribute__((ext_vector_type(4))) u16;
using u16x8 = __attribute__((ext_vector_type(8))) u16;
using s16x8 = __attribute__((ext_vector_type(8))) short;
using f32x4 = __attribute__((ext_vector_type(4))) float;
using u32x4 = __attribute__((ext_vector_type(4))) unsigned int;

__device__ inline float b2f(u16 b) {
    union { unsigned u; float f; } c; c.u = (unsigned)b << 16; return c.f;
}
__device__ inline u16 f2b(float f) {
    union { float f; unsigned u; } c; c.f = f;
    unsigned u = c.u;
    u += 0x7FFFu + ((u >> 16) & 1u);   // round-to-nearest-even
    return (u16)(u >> 16);
}
__device__ inline u16x8 nt_load8(const u16* p) {
    u32x4 v = __builtin_nontemporal_load((const u32x4*)p);
    return *(u16x8*)&v;
}
__device__ inline void nt_store8(u16* p, u16x8 v) {
    __builtin_nontemporal_store(*(u32x4*)&v, (u32x4*)p);
}

// ---------------- in-degree histogram ----------------
__global__ void deg_kernel(const int* __restrict__ dst, int* __restrict__ deg, int E) {
    int e = blockIdx.x * blockDim.x + threadIdx.x;
    if (e < E) atomicAdd(&deg[__builtin_nontemporal_load(dst + e)], 1);
}

// ---------------- hierarchical scan: A (block sums), B (scan sums), C (apply) ----------------
__global__ __launch_bounds__(256) void scanA_kernel(const int* __restrict__ deg,
                                                    int* __restrict__ bsum, int n) {
    __shared__ int red[256];
    int t = threadIdx.x;
    int i0 = blockIdx.x * 1024 + t * 4;
    int s = 0;
    if (i0 + 3 < n) { int4 d = *(const int4*)(deg + i0); s = d.x + d.y + d.z + d.w; }
    else { for (int j = 0; j < 4; j++) if (i0 + j < n) s += deg[i0 + j]; }
    red[t] = s; __syncthreads();
    for (int off = 128; off; off >>= 1) {
        if (t < off) red[t] += red[t + off];
        __syncthreads();
    }
    if (!t) bsum[blockIdx.x] = red[0];
}

__global__ __launch_bounds__(128) void scanB_kernel(int* __restrict__ bsum, int nb) {
    __shared__ int ss[128];
    int t = threadIdx.x;
    int v = (t < nb) ? bsum[t] : 0;
    ss[t] = v; __syncthreads();
    for (int off = 1; off < 128; off <<= 1) {
        int u = (t >= off) ? ss[t - off] : 0;
        __syncthreads();
        ss[t] += u;
        __syncthreads();
    }
    if (t < nb) bsum[t] = ss[t] - v;   // exclusive
}

__global__ __launch_bounds__(256) void scanC_kernel(const int* __restrict__ deg,
                                                    const int* __restrict__ bsum,
                                                    int* __restrict__ row_ptr, int n, int E) {
    __shared__ int ss[256];
    int t = threadIdx.x;
    int i0 = blockIdx.x * 1024 + t * 4;
    int4 d = make_int4(0, 0, 0, 0);
    if (i0 + 3 < n) d = *(const int4*)(deg + i0);
    else {
        if (i0     < n) d.x = deg[i0];
        if (i0 + 1 < n) d.y = deg[i0 + 1];
        if (i0 + 2 < n) d.z = deg[i0 + 2];
        if (i0 + 3 < n) d.w = deg[i0 + 3];
    }
    int s = d.x + d.y + d.z + d.w;
    ss[t] = s; __syncthreads();
    for (int off = 1; off < 256; off <<= 1) {
        int u = (t >= off) ? ss[t - off] : 0;
        __syncthreads();
        ss[t] += u;
        __syncthreads();
    }
    int ex = bsum[blockIdx.x] + ss[t] - s;
    if (i0     < n) row_ptr[i0]     = ex;
    if (i0 + 1 < n) row_ptr[i0 + 1] = ex + d.x;
    if (i0 + 2 < n) row_ptr[i0 + 2] = ex + d.x + d.y;
    if (i0 + 3 < n) row_ptr[i0 + 3] = ex + d.x + d.y + d.z;
    if (i0 == 0) row_ptr[n] = E;
}

// ---------------- CSR fill via per-node cursor ----------------
__global__ void fill_kernel(const int* __restrict__ src, const int* __restrict__ dst,
                            const int* __restrict__ row_ptr, int* __restrict__ cursor,
                            int* __restrict__ adj, int E) {
    int e = blockIdx.x * blockDim.x + threadIdx.x;
    if (e >= E) return;
    int d = __builtin_nontemporal_load(dst + e);
    int pos = atomicAdd(&cursor[d], 1);
    adj[row_ptr[d] + pos] = __builtin_nontemporal_load(src + e);
}

// ---------------- cast x fp32 row-major -> bf16 chunk-major [NC][n][CF] ----------------
__global__ __launch_bounds__(256) void cast_x_kernel(const float* __restrict__ x,
                                                     u16* __restrict__ xc, int n) {
    __shared__ u16 A_s[64][136];
    int t = threadIdx.x;
    int node0 = blockIdx.x * 64;
    #pragma unroll
    for (int i = 0; i < 8; i++) {
        int idx = t + i * 256;          // 2048 float4 pieces
        int r = idx >> 5, q = idx & 31;
        int node = node0 + r;
        f32x4 v = (f32x4)0.f;
        if (node < n) v = __builtin_nontemporal_load((const f32x4*)(x + (size_t)node * NF + q * 4));
        u16x4 o; o[0] = f2b(v[0]); o[1] = f2b(v[1]); o[2] = f2b(v[2]); o[3] = f2b(v[3]);
        *(u16x4*)&A_s[r][q * 4] = o;
    }
    __syncthreads();
    #pragma unroll
    for (int i = 0; i < 4; i++) {
        int idx = t + i * 256;          // 1024 u16x8 pieces
        int c = idx >> 7, r = (idx >> 1) & 63, half = idx & 1;
        int node = node0 + r;
        if (node < n)
            nt_store8(xc + ((size_t)c * n + node) * CF + half * 8,
                      *(u16x8*)&A_s[r][c * CF + half * 8]);
    }
}

// ---------------- weights: fp32 [K][N] -> bf16 transposed [N][K] ----------------
__global__ void cast_wt_kernel(const float* __restrict__ w0, const float* __restrict__ w1,
                               const float* __restrict__ w2, const float* __restrict__ w3,
                               u16* __restrict__ o0, u16* __restrict__ o1,
                               u16* __restrict__ o2, u16* __restrict__ o3) {
    int m = blockIdx.y;
    const float* w = (m == 0) ? w0 : (m == 1) ? w1 : (m == 2) ? w2 : w3;
    u16* o = (m == 0) ? o0 : (m == 1) ? o1 : (m == 2) ? o2 : o3;
    int i = blockIdx.x * 256 + threadIdx.x;
    int k = i >> 7, nc = i & 127;
    o[nc * NF + k] = f2b(w[k * NF + nc]);
}

// ---------------- gather-mean, chunked: grid = (tiles*8), chunk = blockIdx & 7 ----------------
// 256 threads = 128 nodes, 2 lanes/node (16 B = 8 feats each).
__global__ __launch_bounds__(256) void gather_kernel(
    const u16* __restrict__ xc,        // [NC][n][CF]
    const int* __restrict__ row_ptr,
    const int* __restrict__ adj,
    u16* __restrict__ aggc,            // [NC][n][CF]
    int n)
{
    int c = blockIdx.x & 7;
    int tile = blockIdx.x >> 3;
    int node = tile * 128 + (threadIdx.x >> 1);
    if (node >= n) return;
    int half = threadIdx.x & 1;
    const u16* xs = xc + (size_t)c * n * CF + half * 8;

    int beg = __builtin_nontemporal_load(row_ptr + node);
    int end = __builtin_nontemporal_load(row_ptr + node + 1);
    float a[8];
    #pragma unroll
    for (int j = 0; j < 8; j++) a[j] = 0.f;

    int i = beg;
    for (; i + 3 < end; i += 4) {
        int nb0 = __builtin_nontemporal_load(adj + i);
        int nb1 = __builtin_nontemporal_load(adj + i + 1);
        int nb2 = __builtin_nontemporal_load(adj + i + 2);
        int nb3 = __builtin_nontemporal_load(adj + i + 3);
        u16x8 v0 = *(const u16x8*)(xs + (size_t)nb0 * CF);
        u16x8 v1 = *(const u16x8*)(xs + (size_t)nb1 * CF);
        u16x8 v2 = *(const u16x8*)(xs + (size_t)nb2 * CF);
        u16x8 v3 = *(const u16x8*)(xs + (size_t)nb3 * CF);
        #pragma unroll
        for (int j = 0; j < 8; j++)
            a[j] += (b2f(v0[j]) + b2f(v1[j])) + (b2f(v2[j]) + b2f(v3[j]));
    }
    for (; i < end; i++) {
        int nb = __builtin_nontemporal_load(adj + i);
        u16x8 v = *(const u16x8*)(xs + (size_t)nb * CF);
        #pragma unroll
        for (int j = 0; j < 8; j++) a[j] += b2f(v[j]);
    }
    float invd = 1.0f / fmaxf((float)(end - beg), 1.0f);
    u16x8 o;
    #pragma unroll
    for (int j = 0; j < 8; j++) o[j] = f2b(a[j] * invd);
    nt_store8(aggc + ((size_t)c * n + node) * CF + half * 8, o);
}

// ---------------- MFMA GEMM layer: relu(agg@Wl + self@Wr + b) (+FC epilogue) ----------------
// 64 nodes / block, 256 threads (4 waves x 16 output rows).
template <bool FC>
__global__ __launch_bounds__(256) void sage_mfma_kernel(
    const u16* __restrict__ aggc,      // [NC][n][CF] bf16
    const u16* __restrict__ selfc,     // [NC][n][CF] bf16
    const u16* __restrict__ Wtl,       // [128][128] bf16 transposed
    const u16* __restrict__ Wtr,
    const float* __restrict__ bias,
    const float* __restrict__ Wfc,     // [128][2] f32
    const float* __restrict__ bfc,
    u16* __restrict__ houtc,           // [NC][n][CF] bf16 (layer 1)
    float* __restrict__ out,           // [n][2] f32 (layer 2)
    int n)
{
    constexpr int MT = 64;
    constexpr int LDK = 136;
    __shared__ u16 A_s[MT][LDK];       // 17.4 KB
    __shared__ u16 W_s[NF][LDK];       // 34.8 KB

    int t = threadIdx.x;
    int node0 = blockIdx.x * MT;

    // ---- stage Wl + agg tile
    #pragma unroll
    for (int i = 0; i < 8; i++) {
        int idx = t + i * 256;
        int row = idx >> 4, ch = idx & 15;
        *(u16x8*)&W_s[row][ch * 8] = ((const u16x8*)Wtl)[row * 16 + ch];
    }
    #pragma unroll
    for (int i = 0; i < 4; i++) {
        int idx = t + i * 256;
        int c = idx >> 7, r = (idx >> 1) & 63, half = idx & 1;
        int node = node0 + r;
        u16x8 v = (u16x8)0;
        if (node < n) v = nt_load8(aggc + ((size_t)c * n + node) * CF + half * 8);
        *(u16x8*)&A_s[r][c * CF + half * 8] = v;
    }
    __syncthreads();

    int l = t & 63;
    int lr = l & 15;
    int lko = (l >> 4) * 8;
    int m0 = (t >> 6) * 16;

    f32x4 acc[8];
    #pragma unroll
    for (int f = 0; f < 8; f++) acc[f] = (f32x4)0.f;

    #pragma unroll
    for (int ks = 0; ks < NF; ks += 32) {
        s16x8 a = *(const s16x8*)&A_s[m0 + lr][ks + lko];
        #pragma unroll
        for (int f = 0; f < 8; f++) {
            s16x8 b = *(const s16x8*)&W_s[f * 16 + lr][ks + lko];
            acc[f] = __builtin_amdgcn_mfma_f32_16x16x32_bf16(a, b, acc[f], 0, 0, 0);
        }
    }
    __syncthreads();

    // ---- stage Wr + self tile
    #pragma unroll
    for (int i = 0; i < 8; i++) {
        int idx = t + i * 256;
        int row = idx >> 4, ch = idx & 15;
        *(u16x8*)&W_s[row][ch * 8] = ((const u16x8*)Wtr)[row * 16 + ch];
    }
    #pragma unroll
    for (int i = 0; i < 4; i++) {
        int idx = t + i * 256;
        int c = idx >> 7, r = (idx >> 1) & 63, half = idx & 1;
        int node = node0 + r;
        u16x8 v = (u16x8)0;
        if (node < n) v = nt_load8(selfc + ((size_t)c * n + node) * CF + half * 8);
        *(u16x8*)&A_s[r][c * CF + half * 8] = v;
    }
    __syncthreads();

    #pragma unroll
    for (int ks = 0; ks < NF; ks += 32) {
        s16x8 a = *(const s16x8*)&A_s[m0 + lr][ks + lko];
        #pragma unroll
        for (int f = 0; f < 8; f++) {
            s16x8 b = *(const s16x8*)&W_s[f * 16 + lr][ks + lko];
            acc[f] = __builtin_amdgcn_mfma_f32_16x16x32_bf16(a, b, acc[f], 0, 0, 0);
        }
    }

    // ---- bias + relu -> stash bf16 tile in A_s
    __syncthreads();
    int rowb = m0 + (l >> 4) * 4;      // C layout: row=(lane>>4)*4+reg, col=lane&15
    #pragma unroll
    for (int f = 0; f < 8; f++) {
        float bc = bias[f * 16 + lr];
        #pragma unroll
        for (int r = 0; r < 4; r++) {
            float v = fmaxf(acc[f][r] + bc, 0.f);
            A_s[rowb + r][f * 16 + lr] = f2b(v);
        }
    }
    __syncthreads();

    if (!FC) {
        // write h chunk-major (consumed by next-layer gather)
        #pragma unroll
        for (int i = 0; i < 4; i++) {
            int idx = t + i * 256;
            int c = idx >> 7, r = (idx >> 1) & 63, half = idx & 1;
            int node = node0 + r;
            if (node < n)
                nt_store8(houtc + ((size_t)c * n + node) * CF + half * 8,
                          *(u16x8*)&A_s[r][c * CF + half * 8]);
        }
    } else {
        int g = t >> 5, lane = t & 31;
        float2 wfc[4];
        #pragma unroll
        for (int j = 0; j < 4; j++) wfc[j] = ((const float2*)Wfc)[lane * 4 + j];
        float bf0 = bfc[0], bf1 = bfc[1];
        for (int m8 = 0; m8 < 8; m8++) {
            int m = g * 8 + m8;
            float p0 = 0.f, p1 = 0.f;
            #pragma unroll
            for (int j = 0; j < 4; j++) {
                float h = b2f(A_s[m][lane * 4 + j]);
                p0 += h * wfc[j].x;
                p1 += h * wfc[j].y;
            }
            #pragma unroll
            for (int s = 16; s; s >>= 1) {
                p0 += __shfl_down(p0, s, 32);
                p1 += __shfl_down(p1, s, 32);
            }
            int node = node0 + m;
            if (lane == 0 && node < n)
                *(float2*)(out + (size_t)node * 2) = make_float2(p0 + bf0, p1 + bf1);
        }
    }
}

extern "C" void kernel_launch(void* const* d_in, const int* in_sizes, int n_in,
                              void* d_out, int out_size, void* d_ws, size_t ws_size,
                              hipStream_t stream) {
    const float* x   = (const float*)d_in[0];
    const int*   ei  = (const int*)d_in[1];
    const float* W1l = (const float*)d_in[2];
    const float* b1  = (const float*)d_in[3];
    const float* W1r = (const float*)d_in[4];
    const float* W2l = (const float*)d_in[5];
    const float* b2  = (const float*)d_in[6];
    const float* W2r = (const float*)d_in[7];
    const float* Wfc = (const float*)d_in[8];
    const float* bfc = (const float*)d_in[9];

    const int n = in_sizes[0] / NF;   // 100000
    const int E = in_sizes[1] / 2;    // 1600000
    const int* src = ei;
    const int* dst = ei + E;

    // ws: xc | aggc | h1c | 4x Wt | adj | deg | cursor | row_ptr | bsum
    u16* xc     = (u16*)d_ws;
    u16* aggc   = xc   + (size_t)NC * n * CF;
    u16* h1c    = aggc + (size_t)NC * n * CF;
    u16* Wt1l   = h1c  + (size_t)NC * n * CF;
    u16* Wt1r   = Wt1l + NF * NF;
    u16* Wt2l   = Wt1r + NF * NF;
    u16* Wt2r   = Wt2l + NF * NF;
    int* adj    = (int*)(Wt2r + NF * NF);
    int* deg    = adj + E;
    int* cursor = deg + n;
    int* row_ptr= cursor + n;
    int* bsum   = row_ptr + (n + 4);

    (void)hipMemsetAsync(deg, 0, (size_t)2 * n * sizeof(int), stream);

    int eb = (E + 255) / 256;
    int nbA = (n + 1023) / 1024;          // 98 (<=128)
    deg_kernel<<<eb, 256, 0, stream>>>(dst, deg, E);
    scanA_kernel<<<nbA, 256, 0, stream>>>(deg, bsum, n);
    scanB_kernel<<<1, 128, 0, stream>>>(bsum, nbA);
    scanC_kernel<<<nbA, 256, 0, stream>>>(deg, bsum, row_ptr, n, E);
    fill_kernel<<<eb, 256, 0, stream>>>(src, dst, row_ptr, cursor, adj, E);

    int cb = (n + 63) / 64;               // 1563
    cast_x_kernel<<<cb, 256, 0, stream>>>(x, xc, n);
    cast_wt_kernel<<<dim3(64, 4), 256, 0, stream>>>(W1l, W1r, W2l, W2r,
                                                    Wt1l, Wt1r, Wt2l, Wt2r);

    int gtiles = (n + 127) / 128;         // 782
    // layer 1
    gather_kernel<<<gtiles * 8, 256, 0, stream>>>(xc, row_ptr, adj, aggc, n);
    sage_mfma_kernel<false><<<cb, 256, 0, stream>>>(
        aggc, xc, Wt1l, Wt1r, b1, nullptr, nullptr, h1c, nullptr, n);
    // layer 2 + FC
    gather_kernel<<<gtiles * 8, 256, 0, stream>>>(h1c, row_ptr, adj, aggc, n);
    sage_mfma_kernel<true><<<cb, 256, 0, stream>>>(
        aggc, h1c, Wt2l, Wt2r, b2, Wfc, bfc, nullptr, (float*)d_out, n);
}

// Round 6
// 480.468 us; speedup vs baseline: 12.1618x; 1.0115x over previous
//
#include <hip/hip_runtime.h>

#define NF 128          // features
#define NC 8            // chunks (one per XCD)
#define CF 16           // features per chunk

typedef unsigned short u16;
using u16x4 = __attribute__((ext_vector_type(4))) u16;
using u16x8 = __attribute__((ext_vector_type(8))) u16;
using s16x8 = __attribute__((ext_vector_type(8))) short;
using f32x4 = __attribute__((ext_vector_type(4))) float;
using u32x4 = __attribute__((ext_vector_type(4))) unsigned int;
using i32x4 = __attribute__((ext_vector_type(4))) int;

__device__ inline float b2f(u16 b) {
    union { unsigned u; float f; } c; c.u = (unsigned)b << 16; return c.f;
}
__device__ inline u16 f2b(float f) {
    union { float f; unsigned u; } c; c.f = f;
    unsigned u = c.u;
    u += 0x7FFFu + ((u >> 16) & 1u);   // round-to-nearest-even
    return (u16)(u >> 16);
}
__device__ inline u16x8 nt_load8(const u16* p) {
    u32x4 v = __builtin_nontemporal_load((const u32x4*)p);
    return *(u16x8*)&v;
}
__device__ inline void nt_store8(u16* p, u16x8 v) {
    __builtin_nontemporal_store(*(u32x4*)&v, (u32x4*)p);
}
__device__ inline int padded4(int d) { return (d + 3) & ~3; }

// ---------------- in-degree histogram ----------------
__global__ void deg_kernel(const int* __restrict__ dst, int* __restrict__ deg, int E) {
    int e = blockIdx.x * blockDim.x + threadIdx.x;
    if (e < E) atomicAdd(&deg[__builtin_nontemporal_load(dst + e)], 1);
}

// ---------------- hierarchical scan over PADDED sizes ----------------
__global__ __launch_bounds__(256) void scanA_kernel(const int* __restrict__ deg,
                                                    int* __restrict__ bsum, int n) {
    __shared__ int red[256];
    int t = threadIdx.x;
    int i0 = blockIdx.x * 1024 + t * 4;
    int s = 0;
    if (i0 + 3 < n) {
        int4 d = *(const int4*)(deg + i0);
        s = padded4(d.x) + padded4(d.y) + padded4(d.z) + padded4(d.w);
    } else {
        for (int j = 0; j < 4; j++) if (i0 + j < n) s += padded4(deg[i0 + j]);
    }
    red[t] = s; __syncthreads();
    for (int off = 128; off; off >>= 1) {
        if (t < off) red[t] += red[t + off];
        __syncthreads();
    }
    if (!t) bsum[blockIdx.x] = red[0];
}

__global__ __launch_bounds__(128) void scanB_kernel(int* __restrict__ bsum, int nb) {
    __shared__ int ss[128];
    int t = threadIdx.x;
    int v = (t < nb) ? bsum[t] : 0;
    ss[t] = v; __syncthreads();
    for (int off = 1; off < 128; off <<= 1) {
        int u = (t >= off) ? ss[t - off] : 0;
        __syncthreads();
        ss[t] += u;
        __syncthreads();
    }
    if (t < nb) bsum[t] = ss[t] - v;   // exclusive
}

// writes info[i] = {padded_beg, deg}
__global__ __launch_bounds__(256) void scanC_kernel(const int* __restrict__ deg,
                                                    const int* __restrict__ bsum,
                                                    int* __restrict__ info, int n) {
    __shared__ int ss[256];
    int t = threadIdx.x;
    int i0 = blockIdx.x * 1024 + t * 4;
    int4 d = make_int4(0, 0, 0, 0);
    if (i0 + 3 < n) d = *(const int4*)(deg + i0);
    else {
        if (i0     < n) d.x = deg[i0];
        if (i0 + 1 < n) d.y = deg[i0 + 1];
        if (i0 + 2 < n) d.z = deg[i0 + 2];
        if (i0 + 3 < n) d.w = deg[i0 + 3];
    }
    int px = padded4(d.x), py = padded4(d.y), pz = padded4(d.z), pw = padded4(d.w);
    int s = px + py + pz + pw;
    ss[t] = s; __syncthreads();
    for (int off = 1; off < 256; off <<= 1) {
        int u = (t >= off) ? ss[t - off] : 0;
        __syncthreads();
        ss[t] += u;
        __syncthreads();
    }
    int b0 = bsum[blockIdx.x] + ss[t] - s;
    int b1 = b0 + px, b2 = b1 + py, b3 = b2 + pz;
    if (i0 + 3 < n) {
        i32x4 w0 = {b0, d.x, b1, d.y};
        i32x4 w1 = {b2, d.z, b3, d.w};
        ((i32x4*)info)[i0 / 2]     = w0;
        ((i32x4*)info)[i0 / 2 + 1] = w1;
    } else {
        if (i0     < n) { info[2 * i0]     = b0; info[2 * i0 + 1] = d.x; }
        if (i0 + 1 < n) { info[2 * i0 + 2] = b1; info[2 * i0 + 3] = d.y; }
        if (i0 + 2 < n) { info[2 * i0 + 4] = b2; info[2 * i0 + 5] = d.z; }
        if (i0 + 3 < n) { info[2 * i0 + 6] = b3; info[2 * i0 + 7] = d.w; }
    }
}

// ---------------- CSR fill via per-node cursor (padded offsets) ----------------
__global__ void fill_kernel(const int* __restrict__ src, const int* __restrict__ dst,
                            const int* __restrict__ info, int* __restrict__ cursor,
                            int* __restrict__ adj, int E) {
    int e = blockIdx.x * blockDim.x + threadIdx.x;
    if (e >= E) return;
    int d = __builtin_nontemporal_load(dst + e);
    int pos = atomicAdd(&cursor[d], 1);
    int beg = info[2 * d];
    adj[beg + pos] = __builtin_nontemporal_load(src + e);
}

// ---------------- cast x fp32 row-major -> bf16 chunk-major [NC][n][CF] ----------------
__global__ __launch_bounds__(256) void cast_x_kernel(const float* __restrict__ x,
                                                     u16* __restrict__ xc, int n) {
    __shared__ u16 A_s[64][136];
    int t = threadIdx.x;
    int node0 = blockIdx.x * 64;
    #pragma unroll
    for (int i = 0; i < 8; i++) {
        int idx = t + i * 256;          // 2048 float4 pieces
        int r = idx >> 5, q = idx & 31;
        int node = node0 + r;
        f32x4 v = (f32x4)0.f;
        if (node < n) v = __builtin_nontemporal_load((const f32x4*)(x + (size_t)node * NF + q * 4));
        u16x4 o; o[0] = f2b(v[0]); o[1] = f2b(v[1]); o[2] = f2b(v[2]); o[3] = f2b(v[3]);
        *(u16x4*)&A_s[r][q * 4] = o;
    }
    __syncthreads();
    #pragma unroll
    for (int i = 0; i < 4; i++) {
        int idx = t + i * 256;          // 1024 u16x8 pieces
        int c = idx >> 7, r = (idx >> 1) & 63, half = idx & 1;
        int node = node0 + r;
        if (node < n)
            nt_store8(xc + ((size_t)c * n + node) * CF + half * 8,
                      *(u16x8*)&A_s[r][c * CF + half * 8]);
    }
}

// ---------------- weights: fp32 [K][N] -> bf16 transposed [N][K] ----------------
__global__ void cast_wt_kernel(const float* __restrict__ w0, const float* __restrict__ w1,
                               const float* __restrict__ w2, const float* __restrict__ w3,
                               u16* __restrict__ o0, u16* __restrict__ o1,
                               u16* __restrict__ o2, u16* __restrict__ o3) {
    int m = blockIdx.y;
    const float* w = (m == 0) ? w0 : (m == 1) ? w1 : (m == 2) ? w2 : w3;
    u16* o = (m == 0) ? o0 : (m == 1) ? o1 : (m == 2) ? o2 : o3;
    int i = blockIdx.x * 256 + threadIdx.x;
    int k = i >> 7, nc = i & 127;
    o[nc * NF + k] = f2b(w[k * NF + nc]);
}

// ---------------- gather-mean, chunked + int4 adjacency ----------------
// grid = (tiles*8), chunk = blockIdx & 7; 256 threads = 128 nodes, 2 lanes/node.
__global__ __launch_bounds__(256) void gather_kernel(
    const u16* __restrict__ xc,        // [NC][n][CF]
    const int* __restrict__ info,      // [n]{padded_beg, deg}
    const int* __restrict__ adj,       // padded, 4-aligned rows
    u16* __restrict__ aggc,            // [NC][n][CF]
    int n)
{
    int c = blockIdx.x & 7;
    int tile = blockIdx.x >> 3;
    int node = tile * 128 + (threadIdx.x >> 1);
    if (node >= n) return;
    int half = threadIdx.x & 1;
    const u16* xs = xc + (size_t)c * n * CF + half * 8;

    int2 inf = *(const int2*)(info + 2 * node);
    int beg = inf.x, deg = inf.y;
    const i32x4* ap = (const i32x4*)(adj + beg);   // 16B-aligned (beg % 4 == 0)

    float a[8];
    #pragma unroll
    for (int j = 0; j < 8; j++) a[j] = 0.f;

    auto acc1 = [&](int nb) {
        u16x8 v = *(const u16x8*)(xs + (size_t)nb * CF);
        #pragma unroll
        for (int j = 0; j < 8; j++) a[j] += b2f(v[j]);
    };

    int ng = (deg + 3) >> 2;
    if (ng > 0) {
        i32x4 nb = __builtin_nontemporal_load(ap);
        for (int g = 0; g < ng; g++) {
            i32x4 cur = nb;
            if (g + 1 < ng) nb = __builtin_nontemporal_load(ap + g + 1);
            int e0 = g * 4;
            acc1(cur[0]);                      // always valid: e0 < deg
            if (e0 + 1 < deg) acc1(cur[1]);
            if (e0 + 2 < deg) acc1(cur[2]);
            if (e0 + 3 < deg) acc1(cur[3]);
        }
    }
    float invd = 1.0f / fmaxf((float)deg, 1.0f);
    u16x8 o;
    #pragma unroll
    for (int j = 0; j < 8; j++) o[j] = f2b(a[j] * invd);
    nt_store8(aggc + ((size_t)c * n + node) * CF + half * 8, o);
}

// ---------------- MFMA GEMM layer: relu(agg@Wl + self@Wr + b) (+FC epilogue) ----------------
// 64 nodes / block, 256 threads (4 waves x 16 output rows).
template <bool FC>
__global__ __launch_bounds__(256) void sage_mfma_kernel(
    const u16* __restrict__ aggc,      // [NC][n][CF] bf16
    const u16* __restrict__ selfc,     // [NC][n][CF] bf16
    const u16* __restrict__ Wtl,       // [128][128] bf16 transposed
    const u16* __restrict__ Wtr,
    const float* __restrict__ bias,
    const float* __restrict__ Wfc,     // [128][2] f32
    const float* __restrict__ bfc,
    u16* __restrict__ houtc,           // [NC][n][CF] bf16 (layer 1)
    float* __restrict__ out,           // [n][2] f32 (layer 2)
    int n)
{
    constexpr int MT = 64;
    constexpr int LDK = 136;
    __shared__ u16 A_s[MT][LDK];       // 17.4 KB
    __shared__ u16 W_s[NF][LDK];       // 34.8 KB

    int t = threadIdx.x;
    int node0 = blockIdx.x * MT;

    // ---- stage Wl + agg tile
    #pragma unroll
    for (int i = 0; i < 8; i++) {
        int idx = t + i * 256;
        int row = idx >> 4, ch = idx & 15;
        *(u16x8*)&W_s[row][ch * 8] = ((const u16x8*)Wtl)[row * 16 + ch];
    }
    #pragma unroll
    for (int i = 0; i < 4; i++) {
        int idx = t + i * 256;
        int c = idx >> 7, r = (idx >> 1) & 63, half = idx & 1;
        int node = node0 + r;
        u16x8 v = (u16x8)0;
        if (node < n) v = nt_load8(aggc + ((size_t)c * n + node) * CF + half * 8);
        *(u16x8*)&A_s[r][c * CF + half * 8] = v;
    }
    __syncthreads();

    int l = t & 63;
    int lr = l & 15;
    int lko = (l >> 4) * 8;
    int m0 = (t >> 6) * 16;

    f32x4 acc[8];
    #pragma unroll
    for (int f = 0; f < 8; f++) acc[f] = (f32x4)0.f;

    #pragma unroll
    for (int ks = 0; ks < NF; ks += 32) {
        s16x8 a = *(const s16x8*)&A_s[m0 + lr][ks + lko];
        #pragma unroll
        for (int f = 0; f < 8; f++) {
            s16x8 b = *(const s16x8*)&W_s[f * 16 + lr][ks + lko];
            acc[f] = __builtin_amdgcn_mfma_f32_16x16x32_bf16(a, b, acc[f], 0, 0, 0);
        }
    }
    __syncthreads();

    // ---- stage Wr + self tile
    #pragma unroll
    for (int i = 0; i < 8; i++) {
        int idx = t + i * 256;
        int row = idx >> 4, ch = idx & 15;
        *(u16x8*)&W_s[row][ch * 8] = ((const u16x8*)Wtr)[row * 16 + ch];
    }
    #pragma unroll
    for (int i = 0; i < 4; i++) {
        int idx = t + i * 256;
        int c = idx >> 7, r = (idx >> 1) & 63, half = idx & 1;
        int node = node0 + r;
        u16x8 v = (u16x8)0;
        if (node < n) v = nt_load8(selfc + ((size_t)c * n + node) * CF + half * 8);
        *(u16x8*)&A_s[r][c * CF + half * 8] = v;
    }
    __syncthreads();

    #pragma unroll
    for (int ks = 0; ks < NF; ks += 32) {
        s16x8 a = *(const s16x8*)&A_s[m0 + lr][ks + lko];
        #pragma unroll
        for (int f = 0; f < 8; f++) {
            s16x8 b = *(const s16x8*)&W_s[f * 16 + lr][ks + lko];
            acc[f] = __builtin_amdgcn_mfma_f32_16x16x32_bf16(a, b, acc[f], 0, 0, 0);
        }
    }

    // ---- bias + relu -> stash bf16 tile in A_s
    __syncthreads();
    int rowb = m0 + (l >> 4) * 4;      // C layout: row=(lane>>4)*4+reg, col=lane&15
    #pragma unroll
    for (int f = 0; f < 8; f++) {
        float bc = bias[f * 16 + lr];
        #pragma unroll
        for (int r = 0; r < 4; r++) {
            float v = fmaxf(acc[f][r] + bc, 0.f);
            A_s[rowb + r][f * 16 + lr] = f2b(v);
        }
    }
    __syncthreads();

    if (!FC) {
        // write h chunk-major (consumed by next-layer gather)
        #pragma unroll
        for (int i = 0; i < 4; i++) {
            int idx = t + i * 256;
            int c = idx >> 7, r = (idx >> 1) & 63, half = idx & 1;
            int node = node0 + r;
            if (node < n)
                nt_store8(houtc + ((size_t)c * n + node) * CF + half * 8,
                          *(u16x8*)&A_s[r][c * CF + half * 8]);
        }
    } else {
        int g = t >> 5, lane = t & 31;
        float2 wfc[4];
        #pragma unroll
        for (int j = 0; j < 4; j++) wfc[j] = ((const float2*)Wfc)[lane * 4 + j];
        float bf0 = bfc[0], bf1 = bfc[1];
        for (int m8 = 0; m8 < 8; m8++) {
            int m = g * 8 + m8;
            float p0 = 0.f, p1 = 0.f;
            #pragma unroll
            for (int j = 0; j < 4; j++) {
                float h = b2f(A_s[m][lane * 4 + j]);
                p0 += h * wfc[j].x;
                p1 += h * wfc[j].y;
            }
            #pragma unroll
            for (int s = 16; s; s >>= 1) {
                p0 += __shfl_down(p0, s, 32);
                p1 += __shfl_down(p1, s, 32);
            }
            int node = node0 + m;
            if (lane == 0 && node < n)
                *(float2*)(out + (size_t)node * 2) = make_float2(p0 + bf0, p1 + bf1);
        }
    }
}

extern "C" void kernel_launch(void* const* d_in, const int* in_sizes, int n_in,
                              void* d_out, int out_size, void* d_ws, size_t ws_size,
                              hipStream_t stream) {
    const float* x   = (const float*)d_in[0];
    const int*   ei  = (const int*)d_in[1];
    const float* W1l = (const float*)d_in[2];
    const float* b1  = (const float*)d_in[3];
    const float* W1r = (const float*)d_in[4];
    const float* W2l = (const float*)d_in[5];
    const float* b2  = (const float*)d_in[6];
    const float* W2r = (const float*)d_in[7];
    const float* Wfc = (const float*)d_in[8];
    const float* bfc = (const float*)d_in[9];

    const int n = in_sizes[0] / NF;   // 100000
    const int E = in_sizes[1] / 2;    // 1600000
    const int* src = ei;
    const int* dst = ei + E;

    // ws: xc | aggc | h1c | 4x Wt | adj(padded, E+3n) | deg | cursor | info(2n) | bsum
    u16* xc     = (u16*)d_ws;
    u16* aggc   = xc   + (size_t)NC * n * CF;
    u16* h1c    = aggc + (size_t)NC * n * CF;
    u16* Wt1l   = h1c  + (size_t)NC * n * CF;
    u16* Wt1r   = Wt1l + NF * NF;
    u16* Wt2l   = Wt1r + NF * NF;
    u16* Wt2r   = Wt2l + NF * NF;
    int* adj    = (int*)(Wt2r + NF * NF);
    int* deg    = adj + ((size_t)E + 3 * (size_t)n);
    int* cursor = deg + n;
    int* info   = cursor + n;
    int* bsum   = info + 2 * (size_t)n;

    (void)hipMemsetAsync(deg, 0, (size_t)2 * n * sizeof(int), stream);

    int eb = (E + 255) / 256;
    int nbA = (n + 1023) / 1024;          // 98 (<=128)
    deg_kernel<<<eb, 256, 0, stream>>>(dst, deg, E);
    scanA_kernel<<<nbA, 256, 0, stream>>>(deg, bsum, n);
    scanB_kernel<<<1, 128, 0, stream>>>(bsum, nbA);
    scanC_kernel<<<nbA, 256, 0, stream>>>(deg, bsum, info, n);
    fill_kernel<<<eb, 256, 0, stream>>>(src, dst, info, cursor, adj, E);

    int cb = (n + 63) / 64;               // 1563
    cast_x_kernel<<<cb, 256, 0, stream>>>(x, xc, n);
    cast_wt_kernel<<<dim3(64, 4), 256, 0, stream>>>(W1l, W1r, W2l, W2r,
                                                    Wt1l, Wt1r, Wt2l, Wt2r);

    int gtiles = (n + 127) / 128;         // 782
    // layer 1
    gather_kernel<<<gtiles * 8, 256, 0, stream>>>(xc, info, adj, aggc, n);
    sage_mfma_kernel<false><<<cb, 256, 0, stream>>>(
        aggc, xc, Wt1l, Wt1r, b1, nullptr, nullptr, h1c, nullptr, n);
    // layer 2 + FC
    gather_kernel<<<gtiles * 8, 256, 0, stream>>>(h1c, info, adj, aggc, n);
    sage_mfma_kernel<true><<<cb, 256, 0, stream>>>(
        aggc, h1c, Wt2l, Wt2r, b2, Wfc, bfc, nullptr, (float*)d_out, n);
}

// Round 7
// 445.650 us; speedup vs baseline: 13.1120x; 1.0781x over previous
//
#include <hip/hip_runtime.h>

#define NF 128          // features
#define NC 8            // chunks (one per XCD)
#define CF 16           // features per chunk

typedef unsigned short u16;
using u16x4 = __attribute__((ext_vector_type(4))) u16;
using u16x8 = __attribute__((ext_vector_type(8))) u16;
using s16x8 = __attribute__((ext_vector_type(8))) short;
using f32x4 = __attribute__((ext_vector_type(4))) float;
using u32x4 = __attribute__((ext_vector_type(4))) unsigned int;
using i32x4 = __attribute__((ext_vector_type(4))) int;

__device__ inline float b2f(u16 b) {
    union { unsigned u; float f; } c; c.u = (unsigned)b << 16; return c.f;
}
__device__ inline u16 f2b(float f) {
    union { float f; unsigned u; } c; c.f = f;
    unsigned u = c.u;
    u += 0x7FFFu + ((u >> 16) & 1u);   // round-to-nearest-even
    return (u16)(u >> 16);
}
__device__ inline u16x8 nt_load8(const u16* p) {
    u32x4 v = __builtin_nontemporal_load((const u32x4*)p);
    return *(u16x8*)&v;
}
__device__ inline void nt_store8(u16* p, u16x8 v) {
    __builtin_nontemporal_store(*(u32x4*)&v, (u32x4*)p);
}
__device__ inline int padded4(int d) { return (d + 3) & ~3; }

// ---------------- in-degree histogram ----------------
__global__ void deg_kernel(const int* __restrict__ dst, int* __restrict__ deg, int E) {
    int e = blockIdx.x * blockDim.x + threadIdx.x;
    if (e < E) atomicAdd(&deg[__builtin_nontemporal_load(dst + e)], 1);
}

// ---------------- hierarchical scan over PADDED sizes ----------------
__global__ __launch_bounds__(256) void scanA_kernel(const int* __restrict__ deg,
                                                    int* __restrict__ bsum, int n) {
    __shared__ int red[256];
    int t = threadIdx.x;
    int i0 = blockIdx.x * 1024 + t * 4;
    int s = 0;
    if (i0 + 3 < n) {
        int4 d = *(const int4*)(deg + i0);
        s = padded4(d.x) + padded4(d.y) + padded4(d.z) + padded4(d.w);
    } else {
        for (int j = 0; j < 4; j++) if (i0 + j < n) s += padded4(deg[i0 + j]);
    }
    red[t] = s; __syncthreads();
    for (int off = 128; off; off >>= 1) {
        if (t < off) red[t] += red[t + off];
        __syncthreads();
    }
    if (!t) bsum[blockIdx.x] = red[0];
}

__global__ __launch_bounds__(128) void scanB_kernel(int* __restrict__ bsum, int nb) {
    __shared__ int ss[128];
    int t = threadIdx.x;
    int v = (t < nb) ? bsum[t] : 0;
    ss[t] = v; __syncthreads();
    for (int off = 1; off < 128; off <<= 1) {
        int u = (t >= off) ? ss[t - off] : 0;
        __syncthreads();
        ss[t] += u;
        __syncthreads();
    }
    if (t < nb) bsum[t] = ss[t] - v;   // exclusive
}

// writes info[i] = {padded_beg, deg}; also fills adj pad slots with node id n (zero row)
__global__ __launch_bounds__(256) void scanC_kernel(const int* __restrict__ deg,
                                                    const int* __restrict__ bsum,
                                                    int* __restrict__ info,
                                                    int* __restrict__ adj, int n) {
    __shared__ int ss[256];
    int t = threadIdx.x;
    int i0 = blockIdx.x * 1024 + t * 4;
    int4 d = make_int4(0, 0, 0, 0);
    if (i0 + 3 < n) d = *(const int4*)(deg + i0);
    else {
        if (i0     < n) d.x = deg[i0];
        if (i0 + 1 < n) d.y = deg[i0 + 1];
        if (i0 + 2 < n) d.z = deg[i0 + 2];
        if (i0 + 3 < n) d.w = deg[i0 + 3];
    }
    int px = padded4(d.x), py = padded4(d.y), pz = padded4(d.z), pw = padded4(d.w);
    int s = px + py + pz + pw;
    ss[t] = s; __syncthreads();
    for (int off = 1; off < 256; off <<= 1) {
        int u = (t >= off) ? ss[t - off] : 0;
        __syncthreads();
        ss[t] += u;
        __syncthreads();
    }
    int b0 = bsum[blockIdx.x] + ss[t] - s;
    int b1 = b0 + px, b2 = b1 + py, b3 = b2 + pz;
    if (i0 + 3 < n) {
        i32x4 w0 = {b0, d.x, b1, d.y};
        i32x4 w1 = {b2, d.z, b3, d.w};
        ((i32x4*)info)[i0 / 2]     = w0;
        ((i32x4*)info)[i0 / 2 + 1] = w1;
    } else {
        if (i0     < n) { info[2 * i0]     = b0; info[2 * i0 + 1] = d.x; }
        if (i0 + 1 < n) { info[2 * i0 + 2] = b1; info[2 * i0 + 3] = d.y; }
        if (i0 + 2 < n) { info[2 * i0 + 4] = b2; info[2 * i0 + 5] = d.z; }
        if (i0 + 3 < n) { info[2 * i0 + 6] = b3; info[2 * i0 + 7] = d.w; }
    }
    // pad slots -> zero-row index n
    if (i0     < n) for (int p = d.x; p < px; p++) adj[b0 + p] = n;
    if (i0 + 1 < n) for (int p = d.y; p < py; p++) adj[b1 + p] = n;
    if (i0 + 2 < n) for (int p = d.z; p < pz; p++) adj[b2 + p] = n;
    if (i0 + 3 < n) for (int p = d.w; p < pw; p++) adj[b3 + p] = n;
}

// ---------------- CSR fill via per-node cursor (padded offsets) ----------------
__global__ void fill_kernel(const int* __restrict__ src, const int* __restrict__ dst,
                            const int* __restrict__ info, int* __restrict__ cursor,
                            int* __restrict__ adj, int E) {
    int e = blockIdx.x * blockDim.x + threadIdx.x;
    if (e >= E) return;
    int d = __builtin_nontemporal_load(dst + e);
    int pos = atomicAdd(&cursor[d], 1);
    int beg = info[2 * d];
    adj[beg + pos] = __builtin_nontemporal_load(src + e);
}

// ---------------- cast x fp32 row-major -> bf16 chunk-major [NC][n+1][CF]; row n = 0 ----------------
__global__ __launch_bounds__(256) void cast_x_kernel(const float* __restrict__ x,
                                                     u16* __restrict__ xc, int n, int nr) {
    __shared__ u16 A_s[64][136];
    int t = threadIdx.x;
    int node0 = blockIdx.x * 64;
    #pragma unroll
    for (int i = 0; i < 8; i++) {
        int idx = t + i * 256;          // 2048 float4 pieces
        int r = idx >> 5, q = idx & 31;
        int node = node0 + r;
        f32x4 v = (f32x4)0.f;
        if (node < n) v = __builtin_nontemporal_load((const f32x4*)(x + (size_t)node * NF + q * 4));
        u16x4 o; o[0] = f2b(v[0]); o[1] = f2b(v[1]); o[2] = f2b(v[2]); o[3] = f2b(v[3]);
        *(u16x4*)&A_s[r][q * 4] = o;
    }
    __syncthreads();
    #pragma unroll
    for (int i = 0; i < 4; i++) {
        int idx = t + i * 256;          // 1024 u16x8 pieces
        int c = idx >> 7, r = (idx >> 1) & 63, half = idx & 1;
        int node = node0 + r;
        if (node <= n)                  // row n gets zeros (A_s rows >= n are zero)
            nt_store8(xc + ((size_t)c * nr + node) * CF + half * 8,
                      *(u16x8*)&A_s[r][c * CF + half * 8]);
    }
}

// ---------------- weights: fp32 [K][N] -> bf16 transposed [N][K] ----------------
__global__ void cast_wt_kernel(const float* __restrict__ w0, const float* __restrict__ w1,
                               const float* __restrict__ w2, const float* __restrict__ w3,
                               u16* __restrict__ o0, u16* __restrict__ o1,
                               u16* __restrict__ o2, u16* __restrict__ o3) {
    int m = blockIdx.y;
    const float* w = (m == 0) ? w0 : (m == 1) ? w1 : (m == 2) ? w2 : w3;
    u16* o = (m == 0) ? o0 : (m == 1) ? o1 : (m == 2) ? o2 : o3;
    int i = blockIdx.x * 256 + threadIdx.x;
    int k = i >> 7, nc = i & 127;
    o[nc * NF + k] = f2b(w[k * NF + nc]);
}

// ---------------- gather-mean, chunked; branch-free, 8-deep batched loads ----------------
// grid = (tiles*8), chunk = blockIdx & 7; 256 threads = 128 nodes, 2 lanes/node.
__global__ __launch_bounds__(256) void gather_kernel(
    const u16* __restrict__ xc,        // [NC][nr][CF], row n = zeros
    const int* __restrict__ info,      // [n]{padded_beg, deg}
    const int* __restrict__ adj,       // padded, 4-aligned rows; pads point to row n
    u16* __restrict__ aggc,            // [NC][nr][CF]
    int n, int nr)
{
    int c = blockIdx.x & 7;
    int tile = blockIdx.x >> 3;
    int node = tile * 128 + (threadIdx.x >> 1);
    if (node >= n) return;
    int half = threadIdx.x & 1;
    const u16* xs = xc + (size_t)c * nr * CF + half * 8;

    int2 inf = *(const int2*)(info + 2 * node);
    int beg = inf.x, deg = inf.y;
    const i32x4* ap = (const i32x4*)(adj + beg);   // 16B-aligned (beg % 4 == 0)
    int ng = (deg + 3) >> 2;

    float a[8];
    #pragma unroll
    for (int j = 0; j < 8; j++) a[j] = 0.f;

#define ROW(nb) (*(const u16x8*)(xs + (size_t)(nb) * CF))

    i32x4 ia, ib;
    if (ng >= 2) {
        ia = __builtin_nontemporal_load(ap);
        ib = __builtin_nontemporal_load(ap + 1);
    }
    int g = 0;
    while (g + 2 <= ng) {
        i32x4 ca = ia, cb = ib;
        g += 2;
        if (g + 2 <= ng) {   // prefetch next pair under current feature loads
            ia = __builtin_nontemporal_load(ap + g);
            ib = __builtin_nontemporal_load(ap + g + 1);
        }
        u16x8 v0 = ROW(ca[0]), v1 = ROW(ca[1]), v2 = ROW(ca[2]), v3 = ROW(ca[3]);
        u16x8 v4 = ROW(cb[0]), v5 = ROW(cb[1]), v6 = ROW(cb[2]), v7 = ROW(cb[3]);
        #pragma unroll
        for (int j = 0; j < 8; j++)
            a[j] += ((b2f(v0[j]) + b2f(v1[j])) + (b2f(v2[j]) + b2f(v3[j])))
                  + ((b2f(v4[j]) + b2f(v5[j])) + (b2f(v6[j]) + b2f(v7[j])));
    }
    if (g < ng) {
        i32x4 ca = __builtin_nontemporal_load(ap + g);
        u16x8 v0 = ROW(ca[0]), v1 = ROW(ca[1]), v2 = ROW(ca[2]), v3 = ROW(ca[3]);
        #pragma unroll
        for (int j = 0; j < 8; j++)
            a[j] += (b2f(v0[j]) + b2f(v1[j])) + (b2f(v2[j]) + b2f(v3[j]));
    }
#undef ROW

    float invd = 1.0f / fmaxf((float)deg, 1.0f);
    u16x8 o;
    #pragma unroll
    for (int j = 0; j < 8; j++) o[j] = f2b(a[j] * invd);
    nt_store8(aggc + ((size_t)c * nr + node) * CF + half * 8, o);
}

// ---------------- MFMA GEMM layer: relu(agg@Wl + self@Wr + b) (+FC epilogue) ----------------
// 64 nodes / block, 256 threads (4 waves x 16 output rows).
template <bool FC>
__global__ __launch_bounds__(256) void sage_mfma_kernel(
    const u16* __restrict__ aggc,      // [NC][nr][CF] bf16
    const u16* __restrict__ selfc,     // [NC][nr][CF] bf16
    const u16* __restrict__ Wtl,       // [128][128] bf16 transposed
    const u16* __restrict__ Wtr,
    const float* __restrict__ bias,
    const float* __restrict__ Wfc,     // [128][2] f32
    const float* __restrict__ bfc,
    u16* __restrict__ houtc,           // [NC][nr][CF] bf16 (layer 1); row n zeroed
    float* __restrict__ out,           // [n][2] f32 (layer 2)
    int n, int nr)
{
    constexpr int MT = 64;
    constexpr int LDK = 136;
    __shared__ u16 A_s[MT][LDK];       // 17.4 KB
    __shared__ u16 W_s[NF][LDK];       // 34.8 KB

    int t = threadIdx.x;
    int node0 = blockIdx.x * MT;

    // ---- stage Wl + agg tile
    #pragma unroll
    for (int i = 0; i < 8; i++) {
        int idx = t + i * 256;
        int row = idx >> 4, ch = idx & 15;
        *(u16x8*)&W_s[row][ch * 8] = ((const u16x8*)Wtl)[row * 16 + ch];
    }
    #pragma unroll
    for (int i = 0; i < 4; i++) {
        int idx = t + i * 256;
        int c = idx >> 7, r = (idx >> 1) & 63, half = idx & 1;
        int node = node0 + r;
        u16x8 v = (u16x8)0;
        if (node < n) v = nt_load8(aggc + ((size_t)c * nr + node) * CF + half * 8);
        *(u16x8*)&A_s[r][c * CF + half * 8] = v;
    }
    __syncthreads();

    int l = t & 63;
    int lr = l & 15;
    int lko = (l >> 4) * 8;
    int m0 = (t >> 6) * 16;

    f32x4 acc[8];
    #pragma unroll
    for (int f = 0; f < 8; f++) acc[f] = (f32x4)0.f;

    #pragma unroll
    for (int ks = 0; ks < NF; ks += 32) {
        s16x8 a = *(const s16x8*)&A_s[m0 + lr][ks + lko];
        #pragma unroll
        for (int f = 0; f < 8; f++) {
            s16x8 b = *(const s16x8*)&W_s[f * 16 + lr][ks + lko];
            acc[f] = __builtin_amdgcn_mfma_f32_16x16x32_bf16(a, b, acc[f], 0, 0, 0);
        }
    }
    __syncthreads();

    // ---- stage Wr + self tile
    #pragma unroll
    for (int i = 0; i < 8; i++) {
        int idx = t + i * 256;
        int row = idx >> 4, ch = idx & 15;
        *(u16x8*)&W_s[row][ch * 8] = ((const u16x8*)Wtr)[row * 16 + ch];
    }
    #pragma unroll
    for (int i = 0; i < 4; i++) {
        int idx = t + i * 256;
        int c = idx >> 7, r = (idx >> 1) & 63, half = idx & 1;
        int node = node0 + r;
        u16x8 v = (u16x8)0;
        if (node < n) v = nt_load8(selfc + ((size_t)c * nr + node) * CF + half * 8);
        *(u16x8*)&A_s[r][c * CF + half * 8] = v;
    }
    __syncthreads();

    #pragma unroll
    for (int ks = 0; ks < NF; ks += 32) {
        s16x8 a = *(const s16x8*)&A_s[m0 + lr][ks + lko];
        #pragma unroll
        for (int f = 0; f < 8; f++) {
            s16x8 b = *(const s16x8*)&W_s[f * 16 + lr][ks + lko];
            acc[f] = __builtin_amdgcn_mfma_f32_16x16x32_bf16(a, b, acc[f], 0, 0, 0);
        }
    }

    // ---- bias + relu -> stash bf16 tile in A_s
    __syncthreads();
    int rowb = m0 + (l >> 4) * 4;      // C layout: row=(lane>>4)*4+reg, col=lane&15
    #pragma unroll
    for (int f = 0; f < 8; f++) {
        float bc = bias[f * 16 + lr];
        #pragma unroll
        for (int r = 0; r < 4; r++) {
            float v = fmaxf(acc[f][r] + bc, 0.f);
            A_s[rowb + r][f * 16 + lr] = f2b(v);
        }
    }
    __syncthreads();

    if (!FC) {
        // write h chunk-major; node n (zero row) written explicitly
        #pragma unroll
        for (int i = 0; i < 4; i++) {
            int idx = t + i * 256;
            int c = idx >> 7, r = (idx >> 1) & 63, half = idx & 1;
            int node = node0 + r;
            if (node < n)
                nt_store8(houtc + ((size_t)c * nr + node) * CF + half * 8,
                          *(u16x8*)&A_s[r][c * CF + half * 8]);
            else if (node == n)
                nt_store8(houtc + ((size_t)c * nr + node) * CF + half * 8, (u16x8)0);
        }
    } else {
        int g = t >> 5, lane = t & 31;
        float2 wfc[4];
        #pragma unroll
        for (int j = 0; j < 4; j++) wfc[j] = ((const float2*)Wfc)[lane * 4 + j];
        float bf0 = bfc[0], bf1 = bfc[1];
        for (int m8 = 0; m8 < 8; m8++) {
            int m = g * 8 + m8;
            float p0 = 0.f, p1 = 0.f;
            #pragma unroll
            for (int j = 0; j < 4; j++) {
                float h = b2f(A_s[m][lane * 4 + j]);
                p0 += h * wfc[j].x;
                p1 += h * wfc[j].y;
            }
            #pragma unroll
            for (int s = 16; s; s >>= 1) {
                p0 += __shfl_down(p0, s, 32);
                p1 += __shfl_down(p1, s, 32);
            }
            int node = node0 + m;
            if (lane == 0 && node < n)
                *(float2*)(out + (size_t)node * 2) = make_float2(p0 + bf0, p1 + bf1);
        }
    }
}

extern "C" void kernel_launch(void* const* d_in, const int* in_sizes, int n_in,
                              void* d_out, int out_size, void* d_ws, size_t ws_size,
                              hipStream_t stream) {
    const float* x   = (const float*)d_in[0];
    const int*   ei  = (const int*)d_in[1];
    const float* W1l = (const float*)d_in[2];
    const float* b1  = (const float*)d_in[3];
    const float* W1r = (const float*)d_in[4];
    const float* W2l = (const float*)d_in[5];
    const float* b2  = (const float*)d_in[6];
    const float* W2r = (const float*)d_in[7];
    const float* Wfc = (const float*)d_in[8];
    const float* bfc = (const float*)d_in[9];

    const int n = in_sizes[0] / NF;   // 100000
    const int E = in_sizes[1] / 2;    // 1600000
    const int nr = n + 1;             // +1 zero row for pad slots
    const int* src = ei;
    const int* dst = ei + E;

    // ws: xc | aggc | h1c | 4x Wt | adj(padded, E+3n) | deg | cursor | info(2n) | bsum
    u16* xc     = (u16*)d_ws;
    u16* aggc   = xc   + (size_t)NC * nr * CF;
    u16* h1c    = aggc + (size_t)NC * nr * CF;
    u16* Wt1l   = h1c  + (size_t)NC * nr * CF;
    u16* Wt1r   = Wt1l + NF * NF;
    u16* Wt2l   = Wt1r + NF * NF;
    u16* Wt2r   = Wt2l + NF * NF;
    int* adj    = (int*)(Wt2r + NF * NF);
    int* deg    = adj + ((size_t)E + 3 * (size_t)n);
    int* cursor = deg + n;
    int* info   = cursor + n;
    int* bsum   = info + 2 * (size_t)n;

    (void)hipMemsetAsync(deg, 0, (size_t)2 * n * sizeof(int), stream);

    int eb = (E + 255) / 256;
    int nbA = (n + 1023) / 1024;          // 98 (<=128)
    deg_kernel<<<eb, 256, 0, stream>>>(dst, deg, E);
    scanA_kernel<<<nbA, 256, 0, stream>>>(deg, bsum, n);
    scanB_kernel<<<1, 128, 0, stream>>>(bsum, nbA);
    scanC_kernel<<<nbA, 256, 0, stream>>>(deg, bsum, info, adj, n);
    fill_kernel<<<eb, 256, 0, stream>>>(src, dst, info, cursor, adj, E);

    int cb = (nr + 63) / 64;              // covers node n as well
    cast_x_kernel<<<cb, 256, 0, stream>>>(x, xc, n, nr);
    cast_wt_kernel<<<dim3(64, 4), 256, 0, stream>>>(W1l, W1r, W2l, W2r,
                                                    Wt1l, Wt1r, Wt2l, Wt2r);

    int gtiles = (n + 127) / 128;         // 782
    // layer 1
    gather_kernel<<<gtiles * 8, 256, 0, stream>>>(xc, info, adj, aggc, n, nr);
    sage_mfma_kernel<false><<<cb, 256, 0, stream>>>(
        aggc, xc, Wt1l, Wt1r, b1, nullptr, nullptr, h1c, nullptr, n, nr);
    // layer 2 + FC
    gather_kernel<<<gtiles * 8, 256, 0, stream>>>(h1c, info, adj, aggc, n, nr);
    sage_mfma_kernel<true><<<cb, 256, 0, stream>>>(
        aggc, h1c, Wt2l, Wt2r, b2, Wfc, bfc, nullptr, (float*)d_out, n, nr);
}

// Round 8
// 348.135 us; speedup vs baseline: 16.7847x; 1.2801x over previous
//
#include <hip/hip_runtime.h>

#define NF 128          // features

typedef unsigned short u16;
using u16x4 = __attribute__((ext_vector_type(4))) u16;
using u16x8 = __attribute__((ext_vector_type(8))) u16;
using s16x8 = __attribute__((ext_vector_type(8))) short;
using f32x4 = __attribute__((ext_vector_type(4))) float;
using u32x4 = __attribute__((ext_vector_type(4))) unsigned int;
using i32x4 = __attribute__((ext_vector_type(4))) int;

__device__ inline float b2f(u16 b) {
    union { unsigned u; float f; } c; c.u = (unsigned)b << 16; return c.f;
}
__device__ inline u16 f2b(float f) {
    union { float f; unsigned u; } c; c.f = f;
    unsigned u = c.u;
    u += 0x7FFFu + ((u >> 16) & 1u);   // round-to-nearest-even
    return (u16)(u >> 16);
}
__device__ inline u16x8 nt_load8(const u16* p) {
    u32x4 v = __builtin_nontemporal_load((const u32x4*)p);
    return *(u16x8*)&v;
}
__device__ inline void nt_store8(u16* p, u16x8 v) {
    __builtin_nontemporal_store(*(u32x4*)&v, (u32x4*)p);
}
__device__ inline int padded4(int d) { return (d + 3) & ~3; }

// ---------------- in-degree histogram ----------------
__global__ void deg_kernel(const int* __restrict__ dst, int* __restrict__ deg, int E) {
    int e = blockIdx.x * blockDim.x + threadIdx.x;
    if (e < E) atomicAdd(&deg[__builtin_nontemporal_load(dst + e)], 1);
}

// ---------------- hierarchical scan over PADDED sizes ----------------
__global__ __launch_bounds__(256) void scanA_kernel(const int* __restrict__ deg,
                                                    int* __restrict__ bsum, int n) {
    __shared__ int red[256];
    int t = threadIdx.x;
    int i0 = blockIdx.x * 1024 + t * 4;
    int s = 0;
    if (i0 + 3 < n) {
        int4 d = *(const int4*)(deg + i0);
        s = padded4(d.x) + padded4(d.y) + padded4(d.z) + padded4(d.w);
    } else {
        for (int j = 0; j < 4; j++) if (i0 + j < n) s += padded4(deg[i0 + j]);
    }
    red[t] = s; __syncthreads();
    for (int off = 128; off; off >>= 1) {
        if (t < off) red[t] += red[t + off];
        __syncthreads();
    }
    if (!t) bsum[blockIdx.x] = red[0];
}

__global__ __launch_bounds__(128) void scanB_kernel(int* __restrict__ bsum, int nb) {
    __shared__ int ss[128];
    int t = threadIdx.x;
    int v = (t < nb) ? bsum[t] : 0;
    ss[t] = v; __syncthreads();
    for (int off = 1; off < 128; off <<= 1) {
        int u = (t >= off) ? ss[t - off] : 0;
        __syncthreads();
        ss[t] += u;
        __syncthreads();
    }
    if (t < nb) bsum[t] = ss[t] - v;   // exclusive
}

// writes info[i] = {padded_beg, deg}; fills adj pad slots with node id n (zero row)
__global__ __launch_bounds__(256) void scanC_kernel(const int* __restrict__ deg,
                                                    const int* __restrict__ bsum,
                                                    int* __restrict__ info,
                                                    int* __restrict__ adj, int n) {
    __shared__ int ss[256];
    int t = threadIdx.x;
    int i0 = blockIdx.x * 1024 + t * 4;
    int4 d = make_int4(0, 0, 0, 0);
    if (i0 + 3 < n) d = *(const int4*)(deg + i0);
    else {
        if (i0     < n) d.x = deg[i0];
        if (i0 + 1 < n) d.y = deg[i0 + 1];
        if (i0 + 2 < n) d.z = deg[i0 + 2];
        if (i0 + 3 < n) d.w = deg[i0 + 3];
    }
    int px = padded4(d.x), py = padded4(d.y), pz = padded4(d.z), pw = padded4(d.w);
    int s = px + py + pz + pw;
    ss[t] = s; __syncthreads();
    for (int off = 1; off < 256; off <<= 1) {
        int u = (t >= off) ? ss[t - off] : 0;
        __syncthreads();
        ss[t] += u;
        __syncthreads();
    }
    int b0 = bsum[blockIdx.x] + ss[t] - s;
    int b1 = b0 + px, b2 = b1 + py, b3 = b2 + pz;
    if (i0 + 3 < n) {
        i32x4 w0 = {b0, d.x, b1, d.y};
        i32x4 w1 = {b2, d.z, b3, d.w};
        ((i32x4*)info)[i0 / 2]     = w0;
        ((i32x4*)info)[i0 / 2 + 1] = w1;
    } else {
        if (i0     < n) { info[2 * i0]     = b0; info[2 * i0 + 1] = d.x; }
        if (i0 + 1 < n) { info[2 * i0 + 2] = b1; info[2 * i0 + 3] = d.y; }
        if (i0 + 2 < n) { info[2 * i0 + 4] = b2; info[2 * i0 + 5] = d.z; }
        if (i0 + 3 < n) { info[2 * i0 + 6] = b3; info[2 * i0 + 7] = d.w; }
    }
    // pad slots -> zero-row index n
    if (i0     < n) for (int p = d.x; p < px; p++) adj[b0 + p] = n;
    if (i0 + 1 < n) for (int p = d.y; p < py; p++) adj[b1 + p] = n;
    if (i0 + 2 < n) for (int p = d.z; p < pz; p++) adj[b2 + p] = n;
    if (i0 + 3 < n) for (int p = d.w; p < pw; p++) adj[b3 + p] = n;
}

// ---------------- CSR fill via per-node cursor (padded offsets) ----------------
__global__ void fill_kernel(const int* __restrict__ src, const int* __restrict__ dst,
                            const int* __restrict__ info, int* __restrict__ cursor,
                            int* __restrict__ adj, int E) {
    int e = blockIdx.x * blockDim.x + threadIdx.x;
    if (e >= E) return;
    int d = __builtin_nontemporal_load(dst + e);
    int pos = atomicAdd(&cursor[d], 1);
    int beg = info[2 * d];
    adj[beg + pos] = __builtin_nontemporal_load(src + e);
}

// ---------------- cast x fp32 -> bf16 row-major [nr][128]; row n = 0 ----------------
__global__ __launch_bounds__(256) void cast_x_kernel(const float* __restrict__ x,
                                                     u16* __restrict__ xb, int n, int nr) {
    int i = blockIdx.x * 256 + threadIdx.x;   // one per 8 features
    if (i >= nr * (NF / 8)) return;
    int node = i >> 4, ch = i & 15;
    u16x8 o = (u16x8)0;
    if (node < n) {
        const float* p = x + (size_t)node * NF + ch * 8;
        f32x4 v0 = __builtin_nontemporal_load((const f32x4*)p);
        f32x4 v1 = __builtin_nontemporal_load((const f32x4*)(p + 4));
        o[0] = f2b(v0[0]); o[1] = f2b(v0[1]); o[2] = f2b(v0[2]); o[3] = f2b(v0[3]);
        o[4] = f2b(v1[0]); o[5] = f2b(v1[1]); o[6] = f2b(v1[2]); o[7] = f2b(v1[3]);
    }
    *(u16x8*)(xb + (size_t)node * NF + ch * 8) = o;
}

// ---------------- weights: fp32 [K][N] -> bf16 transposed [N][K] ----------------
__global__ void cast_wt_kernel(const float* __restrict__ w0, const float* __restrict__ w1,
                               const float* __restrict__ w2, const float* __restrict__ w3,
                               u16* __restrict__ o0, u16* __restrict__ o1,
                               u16* __restrict__ o2, u16* __restrict__ o3) {
    int m = blockIdx.y;
    const float* w = (m == 0) ? w0 : (m == 1) ? w1 : (m == 2) ? w2 : w3;
    u16* o = (m == 0) ? o0 : (m == 1) ? o1 : (m == 2) ? o2 : o3;
    int i = blockIdx.x * 256 + threadIdx.x;
    int k = i >> 7, nc = i & 127;
    o[nc * NF + k] = f2b(w[k * NF + nc]);
}

// ---------------- gather-mean, row-major; 16 lanes/node; 8-deep batched loads ----------------
// 256 threads = 16 nodes/block.
__global__ __launch_bounds__(256) void gather_kernel(
    const u16* __restrict__ xb,        // [nr][128], row n = zeros
    const int* __restrict__ info,      // [n]{padded_beg, deg}
    const int* __restrict__ adj,       // padded, 4-aligned rows; pads -> row n
    u16* __restrict__ agg,             // [nr][128]
    int n)
{
    int node = blockIdx.x * 16 + (threadIdx.x >> 4);
    if (node >= n) return;
    int lane = threadIdx.x & 15;
    const u16* xs = xb + lane * 8;

    int2 inf = *(const int2*)(info + 2 * node);
    int beg = inf.x, deg = inf.y;
    const i32x4* ap = (const i32x4*)(adj + beg);   // 16B-aligned (beg % 4 == 0)
    int ng = (deg + 3) >> 2;

    float a[8];
    #pragma unroll
    for (int j = 0; j < 8; j++) a[j] = 0.f;

#define ROW(nb) (*(const u16x8*)(xs + (size_t)(nb) * NF))

    i32x4 ia, ib;
    if (ng >= 2) {
        ia = __builtin_nontemporal_load(ap);
        ib = __builtin_nontemporal_load(ap + 1);
    }
    int g = 0;
    while (g + 2 <= ng) {
        i32x4 ca = ia, cb = ib;
        g += 2;
        if (g + 2 <= ng) {   // prefetch next pair under current feature loads
            ia = __builtin_nontemporal_load(ap + g);
            ib = __builtin_nontemporal_load(ap + g + 1);
        }
        u16x8 v0 = ROW(ca[0]), v1 = ROW(ca[1]), v2 = ROW(ca[2]), v3 = ROW(ca[3]);
        u16x8 v4 = ROW(cb[0]), v5 = ROW(cb[1]), v6 = ROW(cb[2]), v7 = ROW(cb[3]);
        #pragma unroll
        for (int j = 0; j < 8; j++)
            a[j] += ((b2f(v0[j]) + b2f(v1[j])) + (b2f(v2[j]) + b2f(v3[j])))
                  + ((b2f(v4[j]) + b2f(v5[j])) + (b2f(v6[j]) + b2f(v7[j])));
    }
    if (g < ng) {
        i32x4 ca = __builtin_nontemporal_load(ap + g);
        u16x8 v0 = ROW(ca[0]), v1 = ROW(ca[1]), v2 = ROW(ca[2]), v3 = ROW(ca[3]);
        #pragma unroll
        for (int j = 0; j < 8; j++)
            a[j] += (b2f(v0[j]) + b2f(v1[j])) + (b2f(v2[j]) + b2f(v3[j]));
    }
#undef ROW

    float invd = 1.0f / fmaxf((float)deg, 1.0f);
    u16x8 o;
    #pragma unroll
    for (int j = 0; j < 8; j++) o[j] = f2b(a[j] * invd);
    *(u16x8*)(agg + (size_t)node * NF + lane * 8) = o;
}

// ---------------- MFMA GEMM layer: relu(agg@Wl + self@Wr + b) (+FC epilogue) ----------------
// 64 nodes / block, 256 threads (4 waves x 16 output rows).
template <bool FC>
__global__ __launch_bounds__(256) void sage_mfma_kernel(
    const u16* __restrict__ agg,       // [nr][128] bf16
    const u16* __restrict__ selfb,     // [nr][128] bf16
    const u16* __restrict__ Wtl,       // [128][128] bf16 transposed
    const u16* __restrict__ Wtr,
    const float* __restrict__ bias,
    const float* __restrict__ Wfc,     // [128][2] f32
    const float* __restrict__ bfc,
    u16* __restrict__ hout,            // [nr][128] bf16 (layer 1); row n zeroed
    float* __restrict__ out,           // [n][2] f32 (layer 2)
    int n)
{
    constexpr int MT = 64;
    constexpr int LDK = 136;
    __shared__ u16 A_s[MT][LDK];       // 17.4 KB
    __shared__ u16 W_s[NF][LDK];       // 34.8 KB

    int t = threadIdx.x;
    int node0 = blockIdx.x * MT;

    // ---- stage Wl + agg tile
    #pragma unroll
    for (int i = 0; i < 8; i++) {
        int idx = t + i * 256;
        int row = idx >> 4, ch = idx & 15;
        *(u16x8*)&W_s[row][ch * 8] = ((const u16x8*)Wtl)[row * 16 + ch];
    }
    #pragma unroll
    for (int i = 0; i < 4; i++) {
        int idx = t + i * 256;
        int row = idx >> 4, ch = idx & 15;
        int node = node0 + row;
        u16x8 v = (u16x8)0;
        if (node < n) v = nt_load8(agg + (size_t)node * NF + ch * 8);
        *(u16x8*)&A_s[row][ch * 8] = v;
    }
    __syncthreads();

    int l = t & 63;
    int lr = l & 15;
    int lko = (l >> 4) * 8;
    int m0 = (t >> 6) * 16;

    f32x4 acc[8];
    #pragma unroll
    for (int f = 0; f < 8; f++) acc[f] = (f32x4)0.f;

    #pragma unroll
    for (int ks = 0; ks < NF; ks += 32) {
        s16x8 a = *(const s16x8*)&A_s[m0 + lr][ks + lko];
        #pragma unroll
        for (int f = 0; f < 8; f++) {
            s16x8 b = *(const s16x8*)&W_s[f * 16 + lr][ks + lko];
            acc[f] = __builtin_amdgcn_mfma_f32_16x16x32_bf16(a, b, acc[f], 0, 0, 0);
        }
    }
    __syncthreads();

    // ---- stage Wr + self tile
    #pragma unroll
    for (int i = 0; i < 8; i++) {
        int idx = t + i * 256;
        int row = idx >> 4, ch = idx & 15;
        *(u16x8*)&W_s[row][ch * 8] = ((const u16x8*)Wtr)[row * 16 + ch];
    }
    #pragma unroll
    for (int i = 0; i < 4; i++) {
        int idx = t + i * 256;
        int row = idx >> 4, ch = idx & 15;
        int node = node0 + row;
        u16x8 v = (u16x8)0;
        if (node < n) v = nt_load8(selfb + (size_t)node * NF + ch * 8);
        *(u16x8*)&A_s[row][ch * 8] = v;
    }
    __syncthreads();

    #pragma unroll
    for (int ks = 0; ks < NF; ks += 32) {
        s16x8 a = *(const s16x8*)&A_s[m0 + lr][ks + lko];
        #pragma unroll
        for (int f = 0; f < 8; f++) {
            s16x8 b = *(const s16x8*)&W_s[f * 16 + lr][ks + lko];
            acc[f] = __builtin_amdgcn_mfma_f32_16x16x32_bf16(a, b, acc[f], 0, 0, 0);
        }
    }

    // ---- bias + relu -> stash bf16 tile in A_s
    __syncthreads();
    int rowb = m0 + (l >> 4) * 4;      // C layout: row=(lane>>4)*4+reg, col=lane&15
    #pragma unroll
    for (int f = 0; f < 8; f++) {
        float bc = bias[f * 16 + lr];
        #pragma unroll
        for (int r = 0; r < 4; r++) {
            float v = fmaxf(acc[f][r] + bc, 0.f);
            A_s[rowb + r][f * 16 + lr] = f2b(v);
        }
    }
    __syncthreads();

    if (!FC) {
        // write h row-major; node n (zero row) written explicitly
        #pragma unroll
        for (int i = 0; i < 4; i++) {
            int idx = t + i * 256;
            int row = idx >> 4, ch = idx & 15;
            int node = node0 + row;
            if (node < n)
                nt_store8(hout + (size_t)node * NF + ch * 8, *(u16x8*)&A_s[row][ch * 8]);
            else if (node == n)
                nt_store8(hout + (size_t)node * NF + ch * 8, (u16x8)0);
        }
    } else {
        int g = t >> 5, lane = t & 31;
        float2 wfc[4];
        #pragma unroll
        for (int j = 0; j < 4; j++) wfc[j] = ((const float2*)Wfc)[lane * 4 + j];
        float bf0 = bfc[0], bf1 = bfc[1];
        for (int m8 = 0; m8 < 8; m8++) {
            int m = g * 8 + m8;
            float p0 = 0.f, p1 = 0.f;
            #pragma unroll
            for (int j = 0; j < 4; j++) {
                float h = b2f(A_s[m][lane * 4 + j]);
                p0 += h * wfc[j].x;
                p1 += h * wfc[j].y;
            }
            #pragma unroll
            for (int s = 16; s; s >>= 1) {
                p0 += __shfl_down(p0, s, 32);
                p1 += __shfl_down(p1, s, 32);
            }
            int node = node0 + m;
            if (lane == 0 && node < n)
                *(float2*)(out + (size_t)node * 2) = make_float2(p0 + bf0, p1 + bf1);
        }
    }
}

extern "C" void kernel_launch(void* const* d_in, const int* in_sizes, int n_in,
                              void* d_out, int out_size, void* d_ws, size_t ws_size,
                              hipStream_t stream) {
    const float* x   = (const float*)d_in[0];
    const int*   ei  = (const int*)d_in[1];
    const float* W1l = (const float*)d_in[2];
    const float* b1  = (const float*)d_in[3];
    const float* W1r = (const float*)d_in[4];
    const float* W2l = (const float*)d_in[5];
    const float* b2  = (const float*)d_in[6];
    const float* W2r = (const float*)d_in[7];
    const float* Wfc = (const float*)d_in[8];
    const float* bfc = (const float*)d_in[9];

    const int n = in_sizes[0] / NF;   // 100000
    const int E = in_sizes[1] / 2;    // 1600000
    const int nr = n + 1;             // +1 zero row for pad slots
    const int* src = ei;
    const int* dst = ei + E;

    // ws: xb | agg | h1 | 4x Wt | adj(padded, E+3n) | deg | cursor | info(2n) | bsum
    u16* xb     = (u16*)d_ws;
    u16* agg    = xb  + (size_t)nr * NF;
    u16* h1     = agg + (size_t)nr * NF;
    u16* Wt1l   = h1  + (size_t)nr * NF;
    u16* Wt1r   = Wt1l + NF * NF;
    u16* Wt2l   = Wt1r + NF * NF;
    u16* Wt2r   = Wt2l + NF * NF;
    int* adj    = (int*)(Wt2r + NF * NF);
    int* deg    = adj + ((size_t)E + 3 * (size_t)n);
    int* cursor = deg + n;
    int* info   = cursor + n;
    int* bsum   = info + 2 * (size_t)n;

    (void)hipMemsetAsync(deg, 0, (size_t)2 * n * sizeof(int), stream);

    int eb = (E + 255) / 256;
    int nbA = (n + 1023) / 1024;          // 98 (<=128)
    deg_kernel<<<eb, 256, 0, stream>>>(dst, deg, E);
    scanA_kernel<<<nbA, 256, 0, stream>>>(deg, bsum, n);
    scanB_kernel<<<1, 128, 0, stream>>>(bsum, nbA);
    scanC_kernel<<<nbA, 256, 0, stream>>>(deg, bsum, info, adj, n);
    fill_kernel<<<eb, 256, 0, stream>>>(src, dst, info, cursor, adj, E);

    cast_x_kernel<<<(nr * (NF / 8) + 255) / 256, 256, 0, stream>>>(x, xb, n, nr);
    cast_wt_kernel<<<dim3(64, 4), 256, 0, stream>>>(W1l, W1r, W2l, W2r,
                                                    Wt1l, Wt1r, Wt2l, Wt2r);

    int gb = (n + 15) / 16;               // 6250
    int cb = (nr + 63) / 64;              // covers node n as well
    // layer 1
    gather_kernel<<<gb, 256, 0, stream>>>(xb, info, adj, agg, n);
    sage_mfma_kernel<false><<<cb, 256, 0, stream>>>(
        agg, xb, Wt1l, Wt1r, b1, nullptr, nullptr, h1, nullptr, n);
    // layer 2 + FC
    gather_kernel<<<gb, 256, 0, stream>>>(h1, info, adj, agg, n);
    sage_mfma_kernel<true><<<cb, 256, 0, stream>>>(
        agg, h1, Wt2l, Wt2r, b2, Wfc, bfc, nullptr, (float*)d_out, n);
}

// Round 9
// 268.483 us; speedup vs baseline: 21.7643x; 1.2967x over previous
//
#include <hip/hip_runtime.h>

#define NF 128          // features
#define SH 9            // bucket shift
#define BNODES 512      // nodes per bucket (1<<SH)
#define MAXNB 256       // max buckets (n <= 131072)

typedef unsigned short u16;
typedef unsigned int u32;
using u16x4 = __attribute__((ext_vector_type(4))) u16;
using u16x8 = __attribute__((ext_vector_type(8))) u16;
using s16x8 = __attribute__((ext_vector_type(8))) short;
using f32x4 = __attribute__((ext_vector_type(4))) float;
using u32x4 = __attribute__((ext_vector_type(4))) u32;
using i32x4 = __attribute__((ext_vector_type(4))) int;

__device__ inline float b2f(u16 b) {
    union { u32 u; float f; } c; c.u = (u32)b << 16; return c.f;
}
__device__ inline u16 f2b(float f) {
    union { float f; u32 u; } c; c.f = f;
    u32 u = c.u;
    u += 0x7FFFu + ((u >> 16) & 1u);   // round-to-nearest-even
    return (u16)(u >> 16);
}
__device__ inline u16x8 nt_load8(const u16* p) {
    u32x4 v = __builtin_nontemporal_load((const u32x4*)p);
    return *(u16x8*)&v;
}
__device__ inline void nt_store8(u16* p, u16x8 v) {
    __builtin_nontemporal_store(*(u32x4*)&v, (u32x4*)p);
}
__device__ inline int padded4(int d) { return (d + 3) & ~3; }

// ---------------- bucket histogram (LDS staged) ----------------
__global__ __launch_bounds__(256) void bhist_kernel(const int* __restrict__ dst,
                                                    int* __restrict__ bcnt, int E, int NB) {
    __shared__ int h[MAXNB];
    int t = threadIdx.x;
    h[t] = 0;
    __syncthreads();
    for (int e = blockIdx.x * 256 + t; e < E; e += gridDim.x * 256)
        atomicAdd(&h[__builtin_nontemporal_load(dst + e) >> SH], 1);
    __syncthreads();
    if (t < NB && h[t]) atomicAdd(&bcnt[t], h[t]);
}

// ---------------- bucket scan: boff (exclusive), gcur init ----------------
__global__ __launch_bounds__(256) void bscan_kernel(const int* __restrict__ bcnt,
                                                    int* __restrict__ boff,
                                                    int* __restrict__ gcur, int NB, int E) {
    __shared__ int ss[256];
    int t = threadIdx.x;
    int v = (t < NB) ? bcnt[t] : 0;
    ss[t] = v; __syncthreads();
    for (int off = 1; off < 256; off <<= 1) {
        int u = (t >= off) ? ss[t - off] : 0;
        __syncthreads();
        ss[t] += u;
        __syncthreads();
    }
    int excl = ss[t] - v;
    if (t < NB) { boff[t] = excl; gcur[t] = excl; }
    if (t == 0) boff[NB] = E;
}

// ---------------- scatter edges into bucket-sorted pairs (LDS staged) ----------------
// 4096 edges / block; packed = (dst&511)<<17 | src  (src < 2^17)
__global__ __launch_bounds__(256) void scatter_kernel(
    const int* __restrict__ src, const int* __restrict__ dst,
    int* __restrict__ gcur, u32* __restrict__ pairs, int E, int NB)
{
    __shared__ int hist[MAXNB];
    __shared__ int cstart[256];
    __shared__ int gbase[MAXNB];
    __shared__ u32 stage[4096];
    __shared__ u16 bmap[4096];
    int t = threadIdx.x;
    int base = blockIdx.x * 4096;

    hist[t] = 0;
    __syncthreads();

    u32 packed[16]; int bb[16]; int loff[16];
    #pragma unroll
    for (int j = 0; j < 16; j++) {
        int e = base + j * 256 + t;
        bb[j] = -1;
        if (e < E) {
            int d = __builtin_nontemporal_load(dst + e);
            int s = __builtin_nontemporal_load(src + e);
            int b = d >> SH;
            bb[j] = b;
            packed[j] = ((u32)(d & (BNODES - 1)) << 17) | (u32)s;
            loff[j] = atomicAdd(&hist[b], 1);
        }
    }
    __syncthreads();

    int hv = hist[t];
    cstart[t] = hv; __syncthreads();
    for (int off = 1; off < 256; off <<= 1) {
        int u = (t >= off) ? cstart[t - off] : 0;
        __syncthreads();
        cstart[t] += u;
        __syncthreads();
    }
    int excl = cstart[t] - hv;
    if (t < NB && hv > 0) gbase[t] = atomicAdd(&gcur[t], hv);
    __syncthreads();
    cstart[t] = excl;
    __syncthreads();

    #pragma unroll
    for (int j = 0; j < 16; j++) if (bb[j] >= 0) {
        int pos = cstart[bb[j]] + loff[j];
        stage[pos] = packed[j];
        bmap[pos] = (u16)bb[j];
    }
    __syncthreads();

    int total = min(4096, E - base);
    for (int k = t; k < total; k += 256) {
        u32 p = stage[k];
        int b = bmap[k];
        pairs[gbase[b] + (k - cstart[b])] = p;
    }
}

// ---------------- per-bucket degree count (LDS) ----------------
__global__ __launch_bounds__(256) void degb_kernel(const u32* __restrict__ pairs,
                                                   const int* __restrict__ boff,
                                                   int* __restrict__ deg, int n) {
    __shared__ int dl[BNODES];
    int b = blockIdx.x, t = threadIdx.x;
    for (int i = t; i < BNODES; i += 256) dl[i] = 0;
    __syncthreads();
    int s = boff[b], e = boff[b + 1];
    for (int k = s + t; k < e; k += 256)
        atomicAdd(&dl[__builtin_nontemporal_load(pairs + k) >> 17], 1);
    __syncthreads();
    int nb0 = b << SH;
    for (int i = t; i < BNODES; i += 256)
        if (nb0 + i < n) deg[nb0 + i] = dl[i];
}

// ---------------- hierarchical scan over PADDED sizes ----------------
__global__ __launch_bounds__(256) void scanA_kernel(const int* __restrict__ deg,
                                                    int* __restrict__ bsum, int n) {
    __shared__ int red[256];
    int t = threadIdx.x;
    int i0 = blockIdx.x * 1024 + t * 4;
    int s = 0;
    if (i0 + 3 < n) {
        int4 d = *(const int4*)(deg + i0);
        s = padded4(d.x) + padded4(d.y) + padded4(d.z) + padded4(d.w);
    } else {
        for (int j = 0; j < 4; j++) if (i0 + j < n) s += padded4(deg[i0 + j]);
    }
    red[t] = s; __syncthreads();
    for (int off = 128; off; off >>= 1) {
        if (t < off) red[t] += red[t + off];
        __syncthreads();
    }
    if (!t) bsum[blockIdx.x] = red[0];
}

__global__ __launch_bounds__(128) void scanB_kernel(int* __restrict__ bsum, int nb) {
    __shared__ int ss[128];
    int t = threadIdx.x;
    int v = (t < nb) ? bsum[t] : 0;
    ss[t] = v; __syncthreads();
    for (int off = 1; off < 128; off <<= 1) {
        int u = (t >= off) ? ss[t - off] : 0;
        __syncthreads();
        ss[t] += u;
        __syncthreads();
    }
    if (t < nb) bsum[t] = ss[t] - v;   // exclusive
}

// writes info[i] = {padded_beg, deg}; fills adj pad slots with node id n (zero row)
__global__ __launch_bounds__(256) void scanC_kernel(const int* __restrict__ deg,
                                                    const int* __restrict__ bsum,
                                                    int* __restrict__ info,
                                                    int* __restrict__ adj, int n) {
    __shared__ int ss[256];
    int t = threadIdx.x;
    int i0 = blockIdx.x * 1024 + t * 4;
    int4 d = make_int4(0, 0, 0, 0);
    if (i0 + 3 < n) d = *(const int4*)(deg + i0);
    else {
        if (i0     < n) d.x = deg[i0];
        if (i0 + 1 < n) d.y = deg[i0 + 1];
        if (i0 + 2 < n) d.z = deg[i0 + 2];
        if (i0 + 3 < n) d.w = deg[i0 + 3];
    }
    int px = padded4(d.x), py = padded4(d.y), pz = padded4(d.z), pw = padded4(d.w);
    int s = px + py + pz + pw;
    ss[t] = s; __syncthreads();
    for (int off = 1; off < 256; off <<= 1) {
        int u = (t >= off) ? ss[t - off] : 0;
        __syncthreads();
        ss[t] += u;
        __syncthreads();
    }
    int b0 = bsum[blockIdx.x] + ss[t] - s;
    int b1 = b0 + px, b2 = b1 + py, b3 = b2 + pz;
    if (i0 + 3 < n) {
        i32x4 w0 = {b0, d.x, b1, d.y};
        i32x4 w1 = {b2, d.z, b3, d.w};
        ((i32x4*)info)[i0 / 2]     = w0;
        ((i32x4*)info)[i0 / 2 + 1] = w1;
    } else {
        if (i0     < n) { info[2 * i0]     = b0; info[2 * i0 + 1] = d.x; }
        if (i0 + 1 < n) { info[2 * i0 + 2] = b1; info[2 * i0 + 3] = d.y; }
        if (i0 + 2 < n) { info[2 * i0 + 4] = b2; info[2 * i0 + 5] = d.z; }
        if (i0 + 3 < n) { info[2 * i0 + 6] = b3; info[2 * i0 + 7] = d.w; }
    }
    // pad slots -> zero-row index n
    if (i0     < n) for (int p = d.x; p < px; p++) adj[b0 + p] = n;
    if (i0 + 1 < n) for (int p = d.y; p < py; p++) adj[b1 + p] = n;
    if (i0 + 2 < n) for (int p = d.z; p < pz; p++) adj[b2 + p] = n;
    if (i0 + 3 < n) for (int p = d.w; p < pw; p++) adj[b3 + p] = n;
}

// ---------------- per-bucket CSR fill (LDS cursors, CU-local adj writes) ----------------
__global__ __launch_bounds__(256) void fill2_kernel(const u32* __restrict__ pairs,
                                                    const int* __restrict__ boff,
                                                    const int* __restrict__ info,
                                                    int* __restrict__ adj, int n) {
    __shared__ int begl[BNODES];
    __shared__ int curl[BNODES];
    int b = blockIdx.x, t = threadIdx.x;
    int nb0 = b << SH;
    for (int i = t; i < BNODES; i += 256) {
        int nd = nb0 + i;
        if (nd < n) begl[i] = info[2 * nd];
        curl[i] = 0;
    }
    __syncthreads();
    int s = boff[b], e = boff[b + 1];
    for (int k = s + t; k < e; k += 256) {
        u32 p = __builtin_nontemporal_load(pairs + k);
        int ld = p >> 17, sr = p & 0x1FFFF;
        int pos = atomicAdd(&curl[ld], 1);
        adj[begl[ld] + pos] = sr;
    }
}

// ---------------- cast x fp32 -> bf16 row-major [nr][128]; row n = 0 ----------------
__global__ __launch_bounds__(256) void cast_x_kernel(const float* __restrict__ x,
                                                     u16* __restrict__ xb, int n, int nr) {
    int i = blockIdx.x * 256 + threadIdx.x;   // one per 8 features
    if (i >= nr * (NF / 8)) return;
    int node = i >> 4, ch = i & 15;
    u16x8 o = (u16x8)0;
    if (node < n) {
        const float* p = x + (size_t)node * NF + ch * 8;
        f32x4 v0 = __builtin_nontemporal_load((const f32x4*)p);
        f32x4 v1 = __builtin_nontemporal_load((const f32x4*)(p + 4));
        o[0] = f2b(v0[0]); o[1] = f2b(v0[1]); o[2] = f2b(v0[2]); o[3] = f2b(v0[3]);
        o[4] = f2b(v1[0]); o[5] = f2b(v1[1]); o[6] = f2b(v1[2]); o[7] = f2b(v1[3]);
    }
    *(u16x8*)(xb + (size_t)node * NF + ch * 8) = o;
}

// ---------------- weights: fp32 [K][N] -> bf16 transposed [N][K] ----------------
__global__ void cast_wt_kernel(const float* __restrict__ w0, const float* __restrict__ w1,
                               const float* __restrict__ w2, const float* __restrict__ w3,
                               u16* __restrict__ o0, u16* __restrict__ o1,
                               u16* __restrict__ o2, u16* __restrict__ o3) {
    int m = blockIdx.y;
    const float* w = (m == 0) ? w0 : (m == 1) ? w1 : (m == 2) ? w2 : w3;
    u16* o = (m == 0) ? o0 : (m == 1) ? o1 : (m == 2) ? o2 : o3;
    int i = blockIdx.x * 256 + threadIdx.x;
    int k = i >> 7, nc = i & 127;
    o[nc * NF + k] = f2b(w[k * NF + nc]);
}

// ---------------- gather-mean, row-major; 16 lanes/node; 8-deep batched loads ----------------
__global__ __launch_bounds__(256) void gather_kernel(
    const u16* __restrict__ xb,        // [nr][128], row n = zeros
    const int* __restrict__ info,      // [n]{padded_beg, deg}
    const int* __restrict__ adj,       // padded, 4-aligned rows; pads -> row n
    u16* __restrict__ agg,             // [nr][128]
    int n)
{
    int node = blockIdx.x * 16 + (threadIdx.x >> 4);
    if (node >= n) return;
    int lane = threadIdx.x & 15;
    const u16* xs = xb + lane * 8;

    int2 inf = *(const int2*)(info + 2 * node);
    int beg = inf.x, deg = inf.y;
    const i32x4* ap = (const i32x4*)(adj + beg);   // 16B-aligned (beg % 4 == 0)
    int ng = (deg + 3) >> 2;

    float a[8];
    #pragma unroll
    for (int j = 0; j < 8; j++) a[j] = 0.f;

#define ROW(nb) (*(const u16x8*)(xs + (size_t)(nb) * NF))

    i32x4 ia, ib;
    if (ng >= 2) {
        ia = __builtin_nontemporal_load(ap);
        ib = __builtin_nontemporal_load(ap + 1);
    }
    int g = 0;
    while (g + 2 <= ng) {
        i32x4 ca = ia, cb = ib;
        g += 2;
        if (g + 2 <= ng) {
            ia = __builtin_nontemporal_load(ap + g);
            ib = __builtin_nontemporal_load(ap + g + 1);
        }
        u16x8 v0 = ROW(ca[0]), v1 = ROW(ca[1]), v2 = ROW(ca[2]), v3 = ROW(ca[3]);
        u16x8 v4 = ROW(cb[0]), v5 = ROW(cb[1]), v6 = ROW(cb[2]), v7 = ROW(cb[3]);
        #pragma unroll
        for (int j = 0; j < 8; j++)
            a[j] += ((b2f(v0[j]) + b2f(v1[j])) + (b2f(v2[j]) + b2f(v3[j])))
                  + ((b2f(v4[j]) + b2f(v5[j])) + (b2f(v6[j]) + b2f(v7[j])));
    }
    if (g < ng) {
        i32x4 ca = __builtin_nontemporal_load(ap + g);
        u16x8 v0 = ROW(ca[0]), v1 = ROW(ca[1]), v2 = ROW(ca[2]), v3 = ROW(ca[3]);
        #pragma unroll
        for (int j = 0; j < 8; j++)
            a[j] += (b2f(v0[j]) + b2f(v1[j])) + (b2f(v2[j]) + b2f(v3[j]));
    }
#undef ROW

    float invd = 1.0f / fmaxf((float)deg, 1.0f);
    u16x8 o;
    #pragma unroll
    for (int j = 0; j < 8; j++) o[j] = f2b(a[j] * invd);
    *(u16x8*)(agg + (size_t)node * NF + lane * 8) = o;
}

// ---------------- MFMA GEMM layer: relu(agg@Wl + self@Wr + b) (+FC epilogue) ----------------
template <bool FC>
__global__ __launch_bounds__(256) void sage_mfma_kernel(
    const u16* __restrict__ agg,       // [nr][128] bf16
    const u16* __restrict__ selfb,     // [nr][128] bf16
    const u16* __restrict__ Wtl,       // [128][128] bf16 transposed
    const u16* __restrict__ Wtr,
    const float* __restrict__ bias,
    const float* __restrict__ Wfc,     // [128][2] f32
    const float* __restrict__ bfc,
    u16* __restrict__ hout,            // [nr][128] bf16 (layer 1); row n zeroed
    float* __restrict__ out,           // [n][2] f32 (layer 2)
    int n)
{
    constexpr int MT = 64;
    constexpr int LDK = 136;
    __shared__ u16 A_s[MT][LDK];
    __shared__ u16 W_s[NF][LDK];

    int t = threadIdx.x;
    int node0 = blockIdx.x * MT;

    #pragma unroll
    for (int i = 0; i < 8; i++) {
        int idx = t + i * 256;
        int row = idx >> 4, ch = idx & 15;
        *(u16x8*)&W_s[row][ch * 8] = ((const u16x8*)Wtl)[row * 16 + ch];
    }
    #pragma unroll
    for (int i = 0; i < 4; i++) {
        int idx = t + i * 256;
        int row = idx >> 4, ch = idx & 15;
        int node = node0 + row;
        u16x8 v = (u16x8)0;
        if (node < n) v = nt_load8(agg + (size_t)node * NF + ch * 8);
        *(u16x8*)&A_s[row][ch * 8] = v;
    }
    __syncthreads();

    int l = t & 63;
    int lr = l & 15;
    int lko = (l >> 4) * 8;
    int m0 = (t >> 6) * 16;

    f32x4 acc[8];
    #pragma unroll
    for (int f = 0; f < 8; f++) acc[f] = (f32x4)0.f;

    #pragma unroll
    for (int ks = 0; ks < NF; ks += 32) {
        s16x8 a = *(const s16x8*)&A_s[m0 + lr][ks + lko];
        #pragma unroll
        for (int f = 0; f < 8; f++) {
            s16x8 b = *(const s16x8*)&W_s[f * 16 + lr][ks + lko];
            acc[f] = __builtin_amdgcn_mfma_f32_16x16x32_bf16(a, b, acc[f], 0, 0, 0);
        }
    }
    __syncthreads();

    #pragma unroll
    for (int i = 0; i < 8; i++) {
        int idx = t + i * 256;
        int row = idx >> 4, ch = idx & 15;
        *(u16x8*)&W_s[row][ch * 8] = ((const u16x8*)Wtr)[row * 16 + ch];
    }
    #pragma unroll
    for (int i = 0; i < 4; i++) {
        int idx = t + i * 256;
        int row = idx >> 4, ch = idx & 15;
        int node = node0 + row;
        u16x8 v = (u16x8)0;
        if (node < n) v = nt_load8(selfb + (size_t)node * NF + ch * 8);
        *(u16x8*)&A_s[row][ch * 8] = v;
    }
    __syncthreads();

    #pragma unroll
    for (int ks = 0; ks < NF; ks += 32) {
        s16x8 a = *(const s16x8*)&A_s[m0 + lr][ks + lko];
        #pragma unroll
        for (int f = 0; f < 8; f++) {
            s16x8 b = *(const s16x8*)&W_s[f * 16 + lr][ks + lko];
            acc[f] = __builtin_amdgcn_mfma_f32_16x16x32_bf16(a, b, acc[f], 0, 0, 0);
        }
    }

    __syncthreads();
    int rowb = m0 + (l >> 4) * 4;      // C layout: row=(lane>>4)*4+reg, col=lane&15
    #pragma unroll
    for (int f = 0; f < 8; f++) {
        float bc = bias[f * 16 + lr];
        #pragma unroll
        for (int r = 0; r < 4; r++) {
            float v = fmaxf(acc[f][r] + bc, 0.f);
            A_s[rowb + r][f * 16 + lr] = f2b(v);
        }
    }
    __syncthreads();

    if (!FC) {
        #pragma unroll
        for (int i = 0; i < 4; i++) {
            int idx = t + i * 256;
            int row = idx >> 4, ch = idx & 15;
            int node = node0 + row;
            if (node < n)
                nt_store8(hout + (size_t)node * NF + ch * 8, *(u16x8*)&A_s[row][ch * 8]);
            else if (node == n)
                nt_store8(hout + (size_t)node * NF + ch * 8, (u16x8)0);
        }
    } else {
        int g = t >> 5, lane = t & 31;
        float2 wfc[4];
        #pragma unroll
        for (int j = 0; j < 4; j++) wfc[j] = ((const float2*)Wfc)[lane * 4 + j];
        float bf0 = bfc[0], bf1 = bfc[1];
        for (int m8 = 0; m8 < 8; m8++) {
            int m = g * 8 + m8;
            float p0 = 0.f, p1 = 0.f;
            #pragma unroll
            for (int j = 0; j < 4; j++) {
                float h = b2f(A_s[m][lane * 4 + j]);
                p0 += h * wfc[j].x;
                p1 += h * wfc[j].y;
            }
            #pragma unroll
            for (int s = 16; s; s >>= 1) {
                p0 += __shfl_down(p0, s, 32);
                p1 += __shfl_down(p1, s, 32);
            }
            int node = node0 + m;
            if (lane == 0 && node < n)
                *(float2*)(out + (size_t)node * 2) = make_float2(p0 + bf0, p1 + bf1);
        }
    }
}

extern "C" void kernel_launch(void* const* d_in, const int* in_sizes, int n_in,
                              void* d_out, int out_size, void* d_ws, size_t ws_size,
                              hipStream_t stream) {
    const float* x   = (const float*)d_in[0];
    const int*   ei  = (const int*)d_in[1];
    const float* W1l = (const float*)d_in[2];
    const float* b1  = (const float*)d_in[3];
    const float* W1r = (const float*)d_in[4];
    const float* W2l = (const float*)d_in[5];
    const float* b2  = (const float*)d_in[6];
    const float* W2r = (const float*)d_in[7];
    const float* Wfc = (const float*)d_in[8];
    const float* bfc = (const float*)d_in[9];

    const int n = in_sizes[0] / NF;   // 100000
    const int E = in_sizes[1] / 2;    // 1600000
    const int nr = n + 1;             // +1 zero row for pad slots
    const int NB = (n + BNODES - 1) >> SH;   // 196
    const int* src = ei;
    const int* dst = ei + E;

    // ws: xb | agg | h1 | 4x Wt | adj(E+3n) | deg(n) | info(2n) | bsum(128) |
    //     bcnt(256) | gcur(256) | boff(257) | pairs(E)
    u16* xb     = (u16*)d_ws;
    u16* agg    = xb  + (size_t)nr * NF;
    u16* h1     = agg + (size_t)nr * NF;
    u16* Wt1l   = h1  + (size_t)nr * NF;
    u16* Wt1r   = Wt1l + NF * NF;
    u16* Wt2l   = Wt1r + NF * NF;
    u16* Wt2r   = Wt2l + NF * NF;
    int* adj    = (int*)(Wt2r + NF * NF);
    int* deg    = adj + ((size_t)E + 3 * (size_t)n);
    int* info   = deg + n;
    int* bsum   = info + 2 * (size_t)n;
    int* bcnt   = bsum + 128;
    int* gcur   = bcnt + 256;
    int* boff   = gcur + 256;
    u32* pairs  = (u32*)(boff + 257);

    // zero bcnt + gcur (contiguous 512 ints)
    (void)hipMemsetAsync(bcnt, 0, 512 * sizeof(int), stream);

    // ---- bucketed CSR build
    bhist_kernel<<<1024, 256, 0, stream>>>(dst, bcnt, E, NB);
    bscan_kernel<<<1, 256, 0, stream>>>(bcnt, boff, gcur, NB, E);
    scatter_kernel<<<(E + 4095) / 4096, 256, 0, stream>>>(src, dst, gcur, pairs, E, NB);
    degb_kernel<<<NB, 256, 0, stream>>>(pairs, boff, deg, n);

    int nbA = (n + 1023) / 1024;          // 98 (<=128)
    scanA_kernel<<<nbA, 256, 0, stream>>>(deg, bsum, n);
    scanB_kernel<<<1, 128, 0, stream>>>(bsum, nbA);
    scanC_kernel<<<nbA, 256, 0, stream>>>(deg, bsum, info, adj, n);
    fill2_kernel<<<NB, 256, 0, stream>>>(pairs, boff, info, adj, n);

    cast_x_kernel<<<(nr * (NF / 8) + 255) / 256, 256, 0, stream>>>(x, xb, n, nr);
    cast_wt_kernel<<<dim3(64, 4), 256, 0, stream>>>(W1l, W1r, W2l, W2r,
                                                    Wt1l, Wt1r, Wt2l, Wt2r);

    int gb = (n + 15) / 16;               // 6250
    int cb = (nr + 63) / 64;
    // layer 1
    gather_kernel<<<gb, 256, 0, stream>>>(xb, info, adj, agg, n);
    sage_mfma_kernel<false><<<cb, 256, 0, stream>>>(
        agg, xb, Wt1l, Wt1r, b1, nullptr, nullptr, h1, nullptr, n);
    // layer 2 + FC
    gather_kernel<<<gb, 256, 0, stream>>>(h1, info, adj, agg, n);
    sage_mfma_kernel<true><<<cb, 256, 0, stream>>>(
        agg, h1, Wt2l, Wt2r, b2, Wfc, bfc, nullptr, (float*)d_out, n);
}